// Round 2
// baseline (15965.575 us; speedup 1.0000x reference)
//
#include <hip/hip_runtime.h>
#include <math.h>

#define CB 64      // batch
#define CT 1024    // time
#define CCH 12     // channels
#define CD 512     // d_model
#define CL 2       // layers
#define CFFN 2048
#define CFCH 256
#define CNC 5
#define CTOPK 20
#define CEPS 1e-5f
#define NSTILE 8   // T/128 s-tiles in k_corr

// ---------------- mean-abs scaler (all batches at once) ----------------
__global__ __launch_bounds__(256) void k_scale(const float* __restrict__ x,
                                               float* __restrict__ sc,
                                               float* __restrict__ lg) {
  int b = blockIdx.x, tid = threadIdx.x;
  float acc[CCH];
#pragma unroll
  for (int c = 0; c < CCH; ++c) acc[c] = 0.f;
  const float* xb = x + (size_t)b * CT * CCH;
  for (int t = tid; t < CT; t += 256) {
    const float* row = xb + t * CCH;
#pragma unroll
    for (int c = 0; c < CCH; ++c) acc[c] += fabsf(row[c]);
  }
  __shared__ float red[256][CCH];
#pragma unroll
  for (int c = 0; c < CCH; ++c) red[tid][c] = acc[c];
  __syncthreads();
  for (int off = 128; off > 0; off >>= 1) {
    if (tid < off) {
#pragma unroll
      for (int c = 0; c < CCH; ++c) red[tid][c] += red[tid + off][c];
    }
    __syncthreads();
  }
  if (tid < CCH) {
    float s = fmaxf(red[0][tid] * (1.0f / CT), 1e-10f);
    sc[b * CCH + tid] = s;
    lg[b * CCH + tid] = logf(s);
  }
}

// ---------------- sinusoidal position table (f64, matches np) ----------------
__global__ __launch_bounds__(512) void k_postab(float* __restrict__ pos) {
  int t = blockIdx.x;
  int d = threadIdx.x;
  double v;
  if (d < 256) {
    double w = pow(10000.0, -((double)d) / 256.0);
    v = sin((double)t * w);
  } else {
    double w = pow(10000.0, -((double)(d - 256)) / 256.0);
    v = cos((double)t * w);
  }
  pos[(size_t)t * CD + d] = (float)v;
}

// ---------------- embedding (K=36 GEMM) + LN fused; chunk-local pointers -------------
__global__ __launch_bounds__(128) void k_embed(const float* __restrict__ x,
                                               const float* __restrict__ sc,
                                               const float* __restrict__ lg,
                                               const float* __restrict__ W,
                                               const float* __restrict__ postab,
                                               const float* __restrict__ g,
                                               const float* __restrict__ beta,
                                               float* __restrict__ h) {
  int row = blockIdx.x;  // local: b*T + t
  int b = row >> 10, t = row & 1023;
  int tid = threadIdx.x;
  __shared__ float xs[CCH], ls[CCH];
  if (tid < CCH) {
    float s = sc[b * CCH + tid];
    xs[tid] = x[(size_t)row * CCH + tid] / s;
    ls[tid] = lg[b * CCH + tid];
  }
  __syncthreads();
  int d0 = tid * 4;
  float4 p = *(const float4*)(postab + (size_t)t * CD + d0);
  float v0 = p.x, v1 = p.y, v2 = p.z, v3 = p.w;
#pragma unroll
  for (int c = 0; c < CCH; ++c) {
    float xc = xs[c], lc = ls[c];
    float4 w0 = *(const float4*)(W + (size_t)c * CD + d0);
    float4 w1 = *(const float4*)(W + (size_t)(24 + c) * CD + d0);
    v0 += xc * w0.x + lc * w1.x;
    v1 += xc * w0.y + lc * w1.y;
    v2 += xc * w0.z + lc * w1.z;
    v3 += xc * w0.w + lc * w1.w;
  }
  float s1 = v0 + v1 + v2 + v3;
  float s2 = v0 * v0 + v1 * v1 + v2 * v2 + v3 * v3;
  for (int off = 32; off > 0; off >>= 1) {
    s1 += __shfl_down(s1, off);
    s2 += __shfl_down(s2, off);
  }
  __shared__ float ws1[2], ws2[2], mv[2];
  int wid = tid >> 6, lane = tid & 63;
  if (lane == 0) { ws1[wid] = s1; ws2[wid] = s2; }
  __syncthreads();
  if (tid == 0) {
    float S1 = ws1[0] + ws1[1], S2 = ws2[0] + ws2[1];
    float mu = S1 * (1.0f / CD);
    float var = S2 * (1.0f / CD) - mu * mu;
    mv[0] = mu;
    mv[1] = 1.0f / sqrtf(var + CEPS);
  }
  __syncthreads();
  float mu = mv[0], ri = mv[1];
  float4 gg = *(const float4*)(g + d0);
  float4 bb = *(const float4*)(beta + d0);
  float4 o;
  o.x = (v0 - mu) * ri * gg.x + bb.x;
  o.y = (v1 - mu) * ri * gg.y + bb.y;
  o.z = (v2 - mu) * ri * gg.z + bb.z;
  o.w = (v3 - mu) * ri * gg.w + bb.w;
  *(float4*)(h + (size_t)row * CD + d0) = o;
}

// ---------------- fp32 tiled GEMM: C = A(MxK) * W(KxN) + bias ------------------------
// EPI: 0 = bias; 1 = bias + exact GELU; 2 = bias + residual R
#define BM 128
#define BN 128
#define BK 16
template <int EPI>
__global__ __launch_bounds__(256) void k_gemm(const float* __restrict__ A,
                                              const float* __restrict__ W,
                                              const float* __restrict__ bias,
                                              const float* __restrict__ R,
                                              float* __restrict__ Cout,
                                              int M, int N, int K) {
  __shared__ float As[BK][BM + 4];  // transposed: As[k][m]
  __shared__ float Bs[BK][BN + 4];
  int tid = threadIdx.x;
  int bn = blockIdx.x, bm = blockIdx.y;
  int m0 = bm * BM, n0 = bn * BN;
  int tx = tid & 15, ty = tid >> 4;
  float acc[8][8];
#pragma unroll
  for (int i = 0; i < 8; ++i)
#pragma unroll
    for (int j = 0; j < 8; ++j) acc[i][j] = 0.f;

  for (int k0 = 0; k0 < K; k0 += BK) {
    {
      int r = tid >> 2, kk = (tid & 3) * 4;
#pragma unroll
      for (int p = 0; p < 2; ++p, r += 64) {
        float4 a = *(const float4*)(A + (size_t)(m0 + r) * K + (k0 + kk));
        As[kk + 0][r] = a.x;
        As[kk + 1][r] = a.y;
        As[kk + 2][r] = a.z;
        As[kk + 3][r] = a.w;
      }
    }
    {
      int kr = tid >> 5, nc = (tid & 31) * 4;
#pragma unroll
      for (int p = 0; p < 2; ++p, kr += 8) {
        float4 bv = *(const float4*)(W + (size_t)(k0 + kr) * N + (n0 + nc));
        *(float4*)&Bs[kr][nc] = bv;
      }
    }
    __syncthreads();
#pragma unroll
    for (int kk = 0; kk < BK; ++kk) {
      float4 a0 = *(const float4*)&As[kk][ty * 8];
      float4 a1 = *(const float4*)&As[kk][ty * 8 + 4];
      float4 b0 = *(const float4*)&Bs[kk][tx * 8];
      float4 b1 = *(const float4*)&Bs[kk][tx * 8 + 4];
      float av[8] = {a0.x, a0.y, a0.z, a0.w, a1.x, a1.y, a1.z, a1.w};
      float bv[8] = {b0.x, b0.y, b0.z, b0.w, b1.x, b1.y, b1.z, b1.w};
#pragma unroll
      for (int i = 0; i < 8; ++i)
#pragma unroll
        for (int j = 0; j < 8; ++j) acc[i][j] += av[i] * bv[j];
    }
    __syncthreads();
  }
  int mrow = m0 + ty * 8, ncol = n0 + tx * 8;
  float4 bb0 = *(const float4*)(bias + ncol);
  float4 bb1 = *(const float4*)(bias + ncol + 4);
  float bv8[8] = {bb0.x, bb0.y, bb0.z, bb0.w, bb1.x, bb1.y, bb1.z, bb1.w};
#pragma unroll
  for (int i = 0; i < 8; ++i) {
    float r8[8] = {0, 0, 0, 0, 0, 0, 0, 0};
    if (EPI == 2) {
      float4 r0 = *(const float4*)(R + (size_t)(mrow + i) * N + ncol);
      float4 r1 = *(const float4*)(R + (size_t)(mrow + i) * N + ncol + 4);
      r8[0] = r0.x; r8[1] = r0.y; r8[2] = r0.z; r8[3] = r0.w;
      r8[4] = r1.x; r8[5] = r1.y; r8[6] = r1.z; r8[7] = r1.w;
    }
    float o[8];
#pragma unroll
    for (int j = 0; j < 8; ++j) {
      float vv = acc[i][j] + bv8[j];
      if (EPI == 1) vv = 0.5f * vv * (1.0f + erff(vv * 0.7071067811865475f));
      if (EPI == 2) vv += r8[j];
      o[j] = vv;
    }
    float4 o0 = {o[0], o[1], o[2], o[3]};
    float4 o1 = {o[4], o[5], o[6], o[7]};
    *(float4*)(Cout + (size_t)(mrow + i) * N + ncol) = o0;
    *(float4*)(Cout + (size_t)(mrow + i) * N + ncol + 4) = o1;
  }
}

// ---------------- circular cross-correlation partials (deterministic, no atomics) ----
// corrP[(b*8+stile)*T + tau] = (1/512) * sum_{s in stile} dot(Q[(tau+s)%T,:], K[s,:])
__global__ __launch_bounds__(256) void k_corr(const float* __restrict__ Q,
                                              const float* __restrict__ Kc,
                                              float* __restrict__ corrP) {
  __shared__ float Qt[16][196];
  __shared__ float Kt[16][132];
  int tid = threadIdx.x;
  int tau0 = blockIdx.x * 64;
  int s0 = blockIdx.y * 128;
  int b = blockIdx.z;
  int tg = tid >> 5;  // 0..7  -> tau base tg*8
  int sg = tid & 31;  // 0..31 -> s base sg*4
  const float* Qb = Q + (size_t)b * CT * CD;
  const float* Kb = Kc + (size_t)b * CT * CD;
  int base = tau0 + s0;
  float acc[8][4];
#pragma unroll
  for (int i = 0; i < 8; ++i)
#pragma unroll
    for (int j = 0; j < 4; ++j) acc[i][j] = 0.f;

  for (int d0 = 0; d0 < CD; d0 += 16) {
    __syncthreads();
    for (int idx = tid; idx < 192 * 4; idx += 256) {
      int i = idx >> 2, dq = (idx & 3) * 4;
      int r = (base + i) & (CT - 1);
      float4 qv = *(const float4*)(Qb + (size_t)r * CD + d0 + dq);
      Qt[dq + 0][i] = qv.x;
      Qt[dq + 1][i] = qv.y;
      Qt[dq + 2][i] = qv.z;
      Qt[dq + 3][i] = qv.w;
    }
    for (int idx = tid; idx < 128 * 4; idx += 256) {
      int i = idx >> 2, dq = (idx & 3) * 4;
      float4 kv = *(const float4*)(Kb + (size_t)(s0 + i) * CD + d0 + dq);
      Kt[dq + 0][i] = kv.x;
      Kt[dq + 1][i] = kv.y;
      Kt[dq + 2][i] = kv.z;
      Kt[dq + 3][i] = kv.w;
    }
    __syncthreads();
#pragma unroll
    for (int dd = 0; dd < 16; ++dd) {
      int qb = tg * 8 + sg * 4;
      float4 q0 = *(const float4*)&Qt[dd][qb];
      float4 q1 = *(const float4*)&Qt[dd][qb + 4];
      float4 q2 = *(const float4*)&Qt[dd][qb + 8];
      float4 k4 = *(const float4*)&Kt[dd][sg * 4];
      float q[12] = {q0.x, q0.y, q0.z, q0.w, q1.x, q1.y,
                     q1.z, q1.w, q2.x, q2.y, q2.z, q2.w};
      float kk[4] = {k4.x, k4.y, k4.z, k4.w};
#pragma unroll
      for (int i = 0; i < 8; ++i)
#pragma unroll
        for (int j = 0; j < 4; ++j) acc[i][j] += q[i + j] * kk[j];
    }
  }
#pragma unroll
  for (int i = 0; i < 8; ++i) {
    float v = acc[i][0] + acc[i][1] + acc[i][2] + acc[i][3];
    for (int off = 16; off > 0; off >>= 1) v += __shfl_down(v, off, 32);
    if (sg == 0)
      corrP[((size_t)b * NSTILE + blockIdx.y) * CT + tau0 + tg * 8 + i] =
          v * (1.0f / 512.0f);
  }
}

// ---------------- top-k (k=20) + softmax weights per (local) batch ----------------
__global__ __launch_bounds__(256) void k_topk(const float* __restrict__ corrP,
                                              float* __restrict__ wts,
                                              int* __restrict__ idxs) {
  int b = blockIdx.x, tid = threadIdx.x;
  __shared__ float vals[CT];
  __shared__ float bestv[256];
  __shared__ int besti[256];
  __shared__ float selv[CTOPK];
  __shared__ int seli[CTOPK];
  for (int i = tid; i < CT; i += 256) {
    float s = 0.f;
#pragma unroll
    for (int st = 0; st < NSTILE; ++st)
      s += corrP[((size_t)b * NSTILE + st) * CT + i];
    vals[i] = s;
  }
  __syncthreads();
  for (int k = 0; k < CTOPK; ++k) {
    float bv = -INFINITY;
    int bi = CT;
    for (int i = tid; i < CT; i += 256) {
      float v = vals[i];
      if (v > bv || (v == bv && i < bi)) { bv = v; bi = i; }
    }
    bestv[tid] = bv;
    besti[tid] = bi;
    __syncthreads();
    for (int off = 128; off > 0; off >>= 1) {
      if (tid < off) {
        float ov = bestv[tid + off];
        int oi = besti[tid + off];
        if (ov > bestv[tid] || (ov == bestv[tid] && oi < besti[tid])) {
          bestv[tid] = ov;
          besti[tid] = oi;
        }
      }
      __syncthreads();
    }
    if (tid == 0) {
      selv[k] = bestv[0];
      seli[k] = besti[0];
      vals[besti[0]] = -INFINITY;
    }
    __syncthreads();
  }
  if (tid == 0) {
    float mx = selv[0], sum = 0.f, e[CTOPK];
    for (int k = 0; k < CTOPK; ++k) {
      e[k] = expf(selv[k] - mx);
      sum += e[k];
    }
    float inv = 1.0f / sum;
    for (int k = 0; k < CTOPK; ++k) {
      wts[b * CTOPK + k] = e[k] * inv;
      idxs[b * CTOPK + k] = seli[k];
    }
  }
}

// ---------------- delay aggregation ----------------
__global__ __launch_bounds__(128) void k_agg(const float* __restrict__ V,
                                             const float* __restrict__ wts,
                                             const int* __restrict__ idxs,
                                             float* __restrict__ out) {
  int row = blockIdx.x;
  int b = row >> 10, t = row & 1023;
  int d0 = threadIdx.x * 4;
  const float* Vb = V + (size_t)b * CT * CD;
  float4 acc = {0.f, 0.f, 0.f, 0.f};
#pragma unroll
  for (int k = 0; k < CTOPK; ++k) {
    float w = wts[b * CTOPK + k];
    int r = t + idxs[b * CTOPK + k];
    if (r >= CT) r -= CT;
    float4 v = *(const float4*)(Vb + (size_t)r * CD + d0);
    acc.x += w * v.x;
    acc.y += w * v.y;
    acc.z += w * v.z;
    acc.w += w * v.w;
  }
  *(float4*)(out + (size_t)row * CD + d0) = acc;
}

// ---------------- LayerNorm (optional residual add) ----------------
template <int ADD>
__global__ __launch_bounds__(128) void k_ln(const float* __restrict__ X,
                                            const float* __restrict__ Rr,
                                            const float* __restrict__ g,
                                            const float* __restrict__ beta,
                                            float* __restrict__ out) {
  int row = blockIdx.x, tid = threadIdx.x;
  int d0 = tid * 4;
  float4 v = *(const float4*)(X + (size_t)row * CD + d0);
  if (ADD) {
    float4 r = *(const float4*)(Rr + (size_t)row * CD + d0);
    v.x += r.x; v.y += r.y; v.z += r.z; v.w += r.w;
  }
  float s1 = v.x + v.y + v.z + v.w;
  float s2 = v.x * v.x + v.y * v.y + v.z * v.z + v.w * v.w;
  for (int off = 32; off > 0; off >>= 1) {
    s1 += __shfl_down(s1, off);
    s2 += __shfl_down(s2, off);
  }
  __shared__ float ws1[2], ws2[2], mv[2];
  int wid = tid >> 6, lane = tid & 63;
  if (lane == 0) { ws1[wid] = s1; ws2[wid] = s2; }
  __syncthreads();
  if (tid == 0) {
    float S1 = ws1[0] + ws1[1], S2 = ws2[0] + ws2[1];
    float mu = S1 * (1.0f / CD);
    float var = S2 * (1.0f / CD) - mu * mu;
    mv[0] = mu;
    mv[1] = 1.0f / sqrtf(var + CEPS);
  }
  __syncthreads();
  float mu = mv[0], ri = mv[1];
  float4 gg = *(const float4*)(g + d0);
  float4 bb = *(const float4*)(beta + d0);
  float4 o;
  o.x = (v.x - mu) * ri * gg.x + bb.x;
  o.y = (v.y - mu) * ri * gg.y + bb.y;
  o.z = (v.z - mu) * ri * gg.z + bb.z;
  o.w = (v.w - mu) * ri * gg.w + bb.w;
  *(float4*)(out + (size_t)row * CD + d0) = o;
}

// ---------------- series decomposition: x - movavg25(x, edge-replicated) ------------
__global__ __launch_bounds__(128) void k_decomp(const float* __restrict__ X,
                                                float* __restrict__ out) {
  int row = blockIdx.x;
  int b = row >> 10, t = row & 1023;
  int d0 = threadIdx.x * 4;
  const float* xb = X + (size_t)b * CT * CD + d0;
  float4 s = {0.f, 0.f, 0.f, 0.f};
#pragma unroll
  for (int j = -12; j <= 12; ++j) {
    int tt = t + j;
    tt = tt < 0 ? 0 : (tt > CT - 1 ? CT - 1 : tt);
    float4 v = *(const float4*)(xb + (size_t)tt * CD);
    s.x += v.x; s.y += v.y; s.z += v.z; s.w += v.w;
  }
  float4 xv = *(const float4*)(xb + (size_t)t * CD);
  const float inv = 1.0f / 25.0f;
  float4 o = {xv.x - s.x * inv, xv.y - s.y * inv, xv.z - s.z * inv, xv.w - s.w * inv};
  *(float4*)(out + (size_t)row * CD + d0) = o;
}

// ---------------- time mean ----------------
__global__ __launch_bounds__(512) void k_meant(const float* __restrict__ X,
                                               float* __restrict__ feat) {
  int b = blockIdx.x, d = threadIdx.x;
  const float* xb = X + (size_t)b * CT * CD + d;
  float acc = 0.f;
  for (int t = 0; t < CT; ++t) acc += xb[(size_t)t * CD];
  feat[b * CD + d] = acc * (1.0f / CT);
}

// ---------------- classification head ----------------
__global__ __launch_bounds__(256) void k_head(const float* __restrict__ feat,
                                              const float* __restrict__ w1,
                                              const float* __restrict__ b1,
                                              const float* __restrict__ w2,
                                              const float* __restrict__ b2,
                                              float* __restrict__ out) {
  int b = blockIdx.x, tid = threadIdx.x;
  __shared__ float f[CD];
  __shared__ float hid[CFCH];
  for (int i = tid; i < CD; i += 256) f[i] = feat[b * CD + i];
  __syncthreads();
  float acc = b1[tid];
  for (int d = 0; d < CD; ++d) acc += f[d] * w1[d * CFCH + tid];
  hid[tid] = fmaxf(acc, 0.f);
  __syncthreads();
  if (tid < CNC) {
    float acc2 = b2[tid];
    for (int j = 0; j < CFCH; ++j) acc2 += hid[j] * w2[j * CNC + tid];
    out[b * CNC + tid] = acc2;
  }
}

// =====================================================================================
extern "C" void kernel_launch(void* const* d_in, const int* in_sizes, int n_in,
                              void* d_out, int out_size, void* d_ws, size_t ws_size,
                              hipStream_t stream) {
  const float* x = (const float*)d_in[0];
  const float* emb_w = (const float*)d_in[1];
  const float* emb_g = (const float*)d_in[2];
  const float* emb_b = (const float*)d_in[3];
  const float* attn_w = (const float*)d_in[4];  // (L,4,D,D)
  const float* attn_b = (const float*)d_in[5];  // (L,4,D)
  const float* ln_g = (const float*)d_in[6];    // (L,2,D)
  const float* ln_bb = (const float*)d_in[7];
  const float* fc1_w = (const float*)d_in[8];   // (L,D,FFN)
  const float* fc1_b = (const float*)d_in[9];
  const float* fc2_w = (const float*)d_in[10];  // (L,FFN,D)
  const float* fc2_b = (const float*)d_in[11];
  const float* hw1 = (const float*)d_in[12];
  const float* hb1 = (const float*)d_in[13];
  const float* hw2 = (const float*)d_in[14];
  const float* hb2 = (const float*)d_in[15];
  float* outp = (float*)d_out;

  // ---- pick the largest batch-chunk Bc that fits ws_size (deterministic per run) ----
  const size_t FIXEDF = (size_t)CT * CD            // postab
                        + 2 * (size_t)CB * CCH     // sc, lg
                        + (size_t)CB * CT * NSTILE // corr partials
                        + 2 * (size_t)CB * CTOPK   // wts, idxs
                        + (size_t)CB * CD          // feat
                        + 64;                      // slack
  int Bc = CB;
  while (Bc > 1) {
    size_t needf = 3 * (size_t)Bc * CT * CD + FIXEDF;
    if (needf * sizeof(float) <= ws_size) break;
    Bc >>= 1;
  }
  const size_t CHF = (size_t)Bc * CT * CD;

  float* ws = (float*)d_ws;
  float* P0 = ws;
  float* P1 = P0 + CHF;
  float* P2 = P1 + CHF;
  float* postab = P2 + CHF;
  float* scb = postab + (size_t)CT * CD;
  float* lgb = scb + (size_t)CB * CCH;
  float* corrP = lgb + (size_t)CB * CCH;
  float* wtb = corrP + (size_t)CB * CT * NSTILE;
  int* idb = (int*)(wtb + (size_t)CB * CTOPK);
  float* featb = (float*)(idb + (size_t)CB * CTOPK);

  k_scale<<<CB, 256, 0, stream>>>(x, scb, lgb);
  k_postab<<<CT, 512, 0, stream>>>(postab);

  for (int b0 = 0; b0 < CB; b0 += Bc) {
    const int Mc = Bc * CT;
    const int MCH = Mc / 4;  // FFN M-sub-chunk so (MCH x FFN) == one full buffer

    k_embed<<<Mc, 128, 0, stream>>>(x + (size_t)b0 * CT * CCH, scb + b0 * CCH,
                                    lgb + b0 * CCH, emb_w, postab, emb_g, emb_b, P0);

    float* h = P0;
    float* bufA = P1;
    float* bufB = P2;
    for (int l = 0; l < CL; ++l) {
      const float* Wq = attn_w + ((size_t)(l * 4 + 0)) * CD * CD;
      const float* Wk = attn_w + ((size_t)(l * 4 + 1)) * CD * CD;
      const float* Wv = attn_w + ((size_t)(l * 4 + 2)) * CD * CD;
      const float* Wo = attn_w + ((size_t)(l * 4 + 3)) * CD * CD;
      const float* bq = attn_b + (size_t)(l * 4 + 0) * CD;
      const float* bk = attn_b + (size_t)(l * 4 + 1) * CD;
      const float* bv = attn_b + (size_t)(l * 4 + 2) * CD;
      const float* bo = attn_b + (size_t)(l * 4 + 3) * CD;
      const float* g0 = ln_g + (size_t)(l * 2 + 0) * CD;
      const float* be0 = ln_bb + (size_t)(l * 2 + 0) * CD;
      const float* g1 = ln_g + (size_t)(l * 2 + 1) * CD;
      const float* be1 = ln_bb + (size_t)(l * 2 + 1) * CD;
      const float* W1 = fc1_w + (size_t)l * CD * CFFN;
      const float* B1 = fc1_b + (size_t)l * CFFN;
      const float* W2 = fc2_w + (size_t)l * CFFN * CD;
      const float* B2 = fc2_b + (size_t)l * CD;

      dim3 gD(CD / BN, Mc / BM);
      // Q, K projections
      k_gemm<0><<<gD, 256, 0, stream>>>(h, Wq, bq, nullptr, bufA, Mc, CD, CD);
      k_gemm<0><<<gD, 256, 0, stream>>>(h, Wk, bk, nullptr, bufB, Mc, CD, CD);
      // correlation partials + top-k (deterministic)
      k_corr<<<dim3(CT / 64, NSTILE, Bc), 256, 0, stream>>>(bufA, bufB, corrP);
      k_topk<<<Bc, 256, 0, stream>>>(corrP, wtb, idb);
      // V projection, delay aggregation, output projection
      k_gemm<0><<<gD, 256, 0, stream>>>(h, Wv, bv, nullptr, bufA, Mc, CD, CD);
      k_agg<<<Mc, 128, 0, stream>>>(bufA, wtb, idb, bufB);
      k_gemm<0><<<gD, 256, 0, stream>>>(bufB, Wo, bo, nullptr, bufA, Mc, CD, CD);
      // residual + LN, decomp
      k_ln<1><<<Mc, 128, 0, stream>>>(h, bufA, g0, be0, h);
      k_decomp<<<Mc, 128, 0, stream>>>(h, bufB);
      // FFN (M-sub-chunked so the 2048-wide intermediate fits in bufA)
      for (int ch = 0; ch < 4; ++ch) {
        const float* in = bufB + (size_t)ch * MCH * CD;
        float* outc = h + (size_t)ch * MCH * CD;
        k_gemm<1><<<dim3(CFFN / BN, MCH / BM), 256, 0, stream>>>(in, W1, B1, nullptr,
                                                                 bufA, MCH, CFFN, CD);
        k_gemm<2><<<dim3(CD / BN, MCH / BM), 256, 0, stream>>>(bufA, W2, B2, in, outc,
                                                               MCH, CD, CFFN);
      }
      k_ln<0><<<Mc, 128, 0, stream>>>(h, nullptr, g1, be1, h);
      k_decomp<<<Mc, 128, 0, stream>>>(h, bufA);
      // rotate buffers
      float* t0 = h;
      h = bufA;
      bufA = bufB;
      bufB = t0;
    }

    k_meant<<<Bc, 512, 0, stream>>>(h, featb);
    k_head<<<Bc, 256, 0, stream>>>(featb, hw1, hb1, hw2, hb2, outp + (size_t)b0 * CNC);
  }
}

// Round 3
// 10701.852 us; speedup vs baseline: 1.4919x; 1.4919x over previous
//
#include <hip/hip_runtime.h>
#include <math.h>

#define CB 64      // batch
#define CT 1024    // time
#define CCH 12     // channels
#define CD 512     // d_model
#define CL 2       // layers
#define CFFN 2048
#define CFCH 256
#define CNC 5
#define CTOPK 20
#define CEPS 1e-5f

typedef __attribute__((ext_vector_type(8))) short bfrag;
typedef __attribute__((ext_vector_type(4))) float ffrag;

__device__ inline ushort bf16r(float f) {
  unsigned u = __float_as_uint(f);
  unsigned r = (u + 0x7FFFu + ((u >> 16) & 1u)) >> 16;
  return (ushort)r;
}
__device__ inline float bf16f(ushort h) { return __uint_as_float(((unsigned)h) << 16); }

// ---------------- mean-abs scaler ----------------
__global__ __launch_bounds__(256) void k_scale(const float* __restrict__ x,
                                               float* __restrict__ sc,
                                               float* __restrict__ lg) {
  int b = blockIdx.x, tid = threadIdx.x;
  float acc[CCH];
#pragma unroll
  for (int c = 0; c < CCH; ++c) acc[c] = 0.f;
  const float* xb = x + (size_t)b * CT * CCH;
  for (int t = tid; t < CT; t += 256) {
    const float* row = xb + t * CCH;
#pragma unroll
    for (int c = 0; c < CCH; ++c) acc[c] += fabsf(row[c]);
  }
  __shared__ float red[256][CCH];
#pragma unroll
  for (int c = 0; c < CCH; ++c) red[tid][c] = acc[c];
  __syncthreads();
  for (int off = 128; off > 0; off >>= 1) {
    if (tid < off) {
#pragma unroll
      for (int c = 0; c < CCH; ++c) red[tid][c] += red[tid + off][c];
    }
    __syncthreads();
  }
  if (tid < CCH) {
    float s = fmaxf(red[0][tid] * (1.0f / CT), 1e-10f);
    sc[b * CCH + tid] = s;
    lg[b * CCH + tid] = logf(s);
  }
}

// ---------------- sinusoidal position table (f64, matches np) ----------------
__global__ __launch_bounds__(512) void k_postab(float* __restrict__ pos) {
  int t = blockIdx.x;
  int d = threadIdx.x;
  double v;
  if (d < 256) {
    double w = pow(10000.0, -((double)d) / 256.0);
    v = sin((double)t * w);
  } else {
    double w = pow(10000.0, -((double)(d - 256)) / 256.0);
    v = cos((double)t * w);
  }
  pos[(size_t)t * CD + d] = (float)v;
}

// ---------------- embedding (K=36 GEMM) + LN fused ----------------
__global__ __launch_bounds__(128) void k_embed(const float* __restrict__ x,
                                               const float* __restrict__ sc,
                                               const float* __restrict__ lg,
                                               const float* __restrict__ W,
                                               const float* __restrict__ postab,
                                               const float* __restrict__ g,
                                               const float* __restrict__ beta,
                                               float* __restrict__ h) {
  int row = blockIdx.x;  // local: b*T + t
  int b = row >> 10, t = row & 1023;
  int tid = threadIdx.x;
  __shared__ float xs[CCH], ls[CCH];
  if (tid < CCH) {
    float s = sc[b * CCH + tid];
    xs[tid] = x[(size_t)row * CCH + tid] / s;
    ls[tid] = lg[b * CCH + tid];
  }
  __syncthreads();
  int d0 = tid * 4;
  float4 p = *(const float4*)(postab + (size_t)t * CD + d0);
  float v0 = p.x, v1 = p.y, v2 = p.z, v3 = p.w;
#pragma unroll
  for (int c = 0; c < CCH; ++c) {
    float xc = xs[c], lc = ls[c];
    float4 w0 = *(const float4*)(W + (size_t)c * CD + d0);
    float4 w1 = *(const float4*)(W + (size_t)(24 + c) * CD + d0);
    v0 += xc * w0.x + lc * w1.x;
    v1 += xc * w0.y + lc * w1.y;
    v2 += xc * w0.z + lc * w1.z;
    v3 += xc * w0.w + lc * w1.w;
  }
  float s1 = v0 + v1 + v2 + v3;
  float s2 = v0 * v0 + v1 * v1 + v2 * v2 + v3 * v3;
  for (int off = 32; off > 0; off >>= 1) {
    s1 += __shfl_down(s1, off);
    s2 += __shfl_down(s2, off);
  }
  __shared__ float ws1[2], ws2[2], mv[2];
  int wid = tid >> 6, lane = tid & 63;
  if (lane == 0) { ws1[wid] = s1; ws2[wid] = s2; }
  __syncthreads();
  if (tid == 0) {
    float S1 = ws1[0] + ws1[1], S2 = ws2[0] + ws2[1];
    float mu = S1 * (1.0f / CD);
    float var = S2 * (1.0f / CD) - mu * mu;
    mv[0] = mu;
    mv[1] = 1.0f / sqrtf(var + CEPS);
  }
  __syncthreads();
  float mu = mv[0], ri = mv[1];
  float4 gg = *(const float4*)(g + d0);
  float4 bb = *(const float4*)(beta + d0);
  float4 o;
  o.x = (v0 - mu) * ri * gg.x + bb.x;
  o.y = (v1 - mu) * ri * gg.y + bb.y;
  o.z = (v2 - mu) * ri * gg.z + bb.z;
  o.w = (v3 - mu) * ri * gg.w + bb.w;
  *(float4*)(h + (size_t)row * CD + d0) = o;
}

// ---------------- fp32 tiled GEMM (kept for Q,K projections — bitwise path) ---------
#define BM 128
#define BN 128
#define BK 16
template <int EPI>
__global__ __launch_bounds__(256) void k_gemm(const float* __restrict__ A,
                                              const float* __restrict__ W,
                                              const float* __restrict__ bias,
                                              const float* __restrict__ R,
                                              float* __restrict__ Cout,
                                              int M, int N, int K) {
  __shared__ float As[BK][BM + 4];
  __shared__ float Bs[BK][BN + 4];
  int tid = threadIdx.x;
  int bn = blockIdx.x, bm = blockIdx.y;
  int m0 = bm * BM, n0 = bn * BN;
  int tx = tid & 15, ty = tid >> 4;
  float acc[8][8];
#pragma unroll
  for (int i = 0; i < 8; ++i)
#pragma unroll
    for (int j = 0; j < 8; ++j) acc[i][j] = 0.f;

  for (int k0 = 0; k0 < K; k0 += BK) {
    {
      int r = tid >> 2, kk = (tid & 3) * 4;
#pragma unroll
      for (int p = 0; p < 2; ++p, r += 64) {
        float4 a = *(const float4*)(A + (size_t)(m0 + r) * K + (k0 + kk));
        As[kk + 0][r] = a.x;
        As[kk + 1][r] = a.y;
        As[kk + 2][r] = a.z;
        As[kk + 3][r] = a.w;
      }
    }
    {
      int kr = tid >> 5, nc = (tid & 31) * 4;
#pragma unroll
      for (int p = 0; p < 2; ++p, kr += 8) {
        float4 bv = *(const float4*)(W + (size_t)(k0 + kr) * N + (n0 + nc));
        *(float4*)&Bs[kr][nc] = bv;
      }
    }
    __syncthreads();
#pragma unroll
    for (int kk = 0; kk < BK; ++kk) {
      float4 a0 = *(const float4*)&As[kk][ty * 8];
      float4 a1 = *(const float4*)&As[kk][ty * 8 + 4];
      float4 b0 = *(const float4*)&Bs[kk][tx * 8];
      float4 b1 = *(const float4*)&Bs[kk][tx * 8 + 4];
      float av[8] = {a0.x, a0.y, a0.z, a0.w, a1.x, a1.y, a1.z, a1.w};
      float bv[8] = {b0.x, b0.y, b0.z, b0.w, b1.x, b1.y, b1.z, b1.w};
#pragma unroll
      for (int i = 0; i < 8; ++i)
#pragma unroll
        for (int j = 0; j < 8; ++j) acc[i][j] += av[i] * bv[j];
    }
    __syncthreads();
  }
  int mrow = m0 + ty * 8, ncol = n0 + tx * 8;
  float4 bb0 = *(const float4*)(bias + ncol);
  float4 bb1 = *(const float4*)(bias + ncol + 4);
  float bv8[8] = {bb0.x, bb0.y, bb0.z, bb0.w, bb1.x, bb1.y, bb1.z, bb1.w};
#pragma unroll
  for (int i = 0; i < 8; ++i) {
    float o[8];
#pragma unroll
    for (int j = 0; j < 8; ++j) {
      float vv = acc[i][j] + bv8[j];
      if (EPI == 1) vv = 0.5f * vv * (1.0f + erff(vv * 0.7071067811865475f));
      o[j] = vv;
    }
    float4 o0 = {o[0], o[1], o[2], o[3]};
    float4 o1 = {o[4], o[5], o[6], o[7]};
    *(float4*)(Cout + (size_t)(mrow + i) * N + ncol) = o0;
    *(float4*)(Cout + (size_t)(mrow + i) * N + ncol + 4) = o1;
  }
}

// ---------------- fp32 NT GEMM: S[b] = Q[b] (1024x512) * K[b]^T --------------------
__global__ __launch_bounds__(256) void k_gemmnt(const float* __restrict__ Q,
                                                const float* __restrict__ Km,
                                                float* __restrict__ S) {
  __shared__ float As[BK][BM + 4];
  __shared__ float Bs[BK][BN + 4];
  int tid = threadIdx.x;
  int b = blockIdx.z;
  int n0 = blockIdx.x * BN, m0 = blockIdx.y * BM;
  const float* A = Q + (size_t)b * CT * CD;
  const float* B = Km + (size_t)b * CT * CD;
  int tx = tid & 15, ty = tid >> 4;
  float acc[8][8];
#pragma unroll
  for (int i = 0; i < 8; ++i)
#pragma unroll
    for (int j = 0; j < 8; ++j) acc[i][j] = 0.f;

  for (int k0 = 0; k0 < CD; k0 += BK) {
    int r = tid >> 2, kk = (tid & 3) * 4;
#pragma unroll
    for (int p = 0; p < 2; ++p, r += 64) {
      float4 a = *(const float4*)(A + (size_t)(m0 + r) * CD + (k0 + kk));
      As[kk + 0][r] = a.x;
      As[kk + 1][r] = a.y;
      As[kk + 2][r] = a.z;
      As[kk + 3][r] = a.w;
      float4 bb = *(const float4*)(B + (size_t)(n0 + r) * CD + (k0 + kk));
      Bs[kk + 0][r] = bb.x;
      Bs[kk + 1][r] = bb.y;
      Bs[kk + 2][r] = bb.z;
      Bs[kk + 3][r] = bb.w;
    }
    __syncthreads();
#pragma unroll
    for (int kk2 = 0; kk2 < BK; ++kk2) {
      float4 a0 = *(const float4*)&As[kk2][ty * 8];
      float4 a1 = *(const float4*)&As[kk2][ty * 8 + 4];
      float4 b0 = *(const float4*)&Bs[kk2][tx * 8];
      float4 b1 = *(const float4*)&Bs[kk2][tx * 8 + 4];
      float av[8] = {a0.x, a0.y, a0.z, a0.w, a1.x, a1.y, a1.z, a1.w};
      float bv[8] = {b0.x, b0.y, b0.z, b0.w, b1.x, b1.y, b1.z, b1.w};
#pragma unroll
      for (int i = 0; i < 8; ++i)
#pragma unroll
        for (int j = 0; j < 8; ++j) acc[i][j] += av[i] * bv[j];
    }
    __syncthreads();
  }
  float* Sb = S + (size_t)b * CT * CT;
  int mrow = m0 + ty * 8, ncol = n0 + tx * 8;
#pragma unroll
  for (int i = 0; i < 8; ++i) {
    float4 o0 = {acc[i][0], acc[i][1], acc[i][2], acc[i][3]};
    float4 o1 = {acc[i][4], acc[i][5], acc[i][6], acc[i][7]};
    *(float4*)(Sb + (size_t)(mrow + i) * CT + ncol) = o0;
    *(float4*)(Sb + (size_t)(mrow + i) * CT + ncol + 4) = o1;
  }
}

// ---------------- diagonal fold: corr[b,tau] = (1/512) sum_j S[b,(tau+j)%T, j] ------
__global__ __launch_bounds__(256) void k_fold(const float* __restrict__ S,
                                              float* __restrict__ corrb) {
  int b = blockIdx.y, tau0 = blockIdx.x * 64;
  int tid = threadIdx.x;
  int tl = tid & 63, p = tid >> 6;
  __shared__ float Sb[128][65];
  __shared__ float red[4][64];
  const float* Sbase = S + (size_t)b * CT * CT;
  float acc = 0.f;
  for (int jc = 0; jc < 16; ++jc) {
    int jbase = jc * 64;
    __syncthreads();
    for (int rnd = 0; rnd < 8; ++rnd) {
      int rr = rnd * 16 + (tid >> 4);
      int c4 = (tid & 15) * 4;
      int gi = (tau0 + jbase + rr) & (CT - 1);
      float4 v = *(const float4*)(Sbase + (size_t)gi * CT + jbase + c4);
      Sb[rr][c4 + 0] = v.x;
      Sb[rr][c4 + 1] = v.y;
      Sb[rr][c4 + 2] = v.z;
      Sb[rr][c4 + 3] = v.w;
    }
    __syncthreads();
#pragma unroll
    for (int q = 0; q < 16; ++q) {
      int jl = p * 16 + q;
      acc += Sb[tl + jl][jl];
    }
  }
  red[p][tl] = acc;
  __syncthreads();
  if (tid < 64) {
    float s = red[0][tid] + red[1][tid] + red[2][tid] + red[3][tid];
    corrb[(size_t)b * CT + tau0 + tid] = s * (1.0f / 512.0f);
  }
}

// ---------------- fp32 -> 2-term bf16 split, row layout [m][2K] = hi|lo --------------
__global__ __launch_bounds__(256) void k_cvta(const float* __restrict__ A,
                                              ushort* __restrict__ A2, int kshift) {
  size_t idx4 = ((size_t)blockIdx.x * 256 + threadIdx.x) * 4;
  int K = 1 << kshift;
  size_t row = idx4 >> kshift;
  int k = (int)(idx4 & (size_t)(K - 1));
  float4 v = *(const float4*)(A + idx4);
  ushort h0 = bf16r(v.x), h1 = bf16r(v.y), h2 = bf16r(v.z), h3 = bf16r(v.w);
  ushort l0 = bf16r(v.x - bf16f(h0));
  ushort l1 = bf16r(v.y - bf16f(h1));
  ushort l2 = bf16r(v.z - bf16f(h2));
  ushort l3 = bf16r(v.w - bf16f(h3));
  ushort* p = A2 + row * (size_t)(2 * K) + k;
  ushort4 hv = {h0, h1, h2, h3};
  ushort4 lv = {l0, l1, l2, l3};
  *(ushort4*)p = hv;
  *(ushort4*)(p + K) = lv;
}

// ---------------- weight convert+transpose: W[K][N] fp32 -> W2[N][2K] bf16 hi|lo ----
__global__ __launch_bounds__(256) void k_cvtw(const float* __restrict__ W,
                                              ushort* __restrict__ W2,
                                              int K, int N) {
  __shared__ float tile[32][33];
  int tx = threadIdx.x & 31, ty = threadIdx.x >> 5;  // ty 0..7
  int n0 = blockIdx.x * 32, k0 = blockIdx.y * 32;
#pragma unroll
  for (int r = 0; r < 4; ++r)
    tile[ty * 4 + r][tx] = W[(size_t)(k0 + ty * 4 + r) * N + n0 + tx];
  __syncthreads();
#pragma unroll
  for (int r = 0; r < 4; ++r) {
    int nl = ty * 4 + r, kl = tx;
    float f = tile[kl][nl];
    ushort hi = bf16r(f);
    ushort lo = bf16r(f - bf16f(hi));
    size_t base = (size_t)(n0 + nl) * (size_t)(2 * K) + k0 + kl;
    W2[base] = hi;
    W2[base + K] = lo;
  }
}

// ---------------- bf16-split MFMA GEMM: C = A*W + bias -------------------------------
// A2: [M][2K] (hi|lo), W2: [N][2K] (hi|lo). EPI: 0=bias, 1=bias+GELU, 2=bias+residual
#define LSTR 40  // LDS row stride in bf16 elems (16B-aligned, conflict-breaking)
template <int EPI>
__global__ __launch_bounds__(256) void k_gemm2(const ushort* __restrict__ A2,
                                               const ushort* __restrict__ W2,
                                               const float* __restrict__ bias,
                                               const float* __restrict__ R,
                                               float* __restrict__ Cout,
                                               int M, int N, int K) {
  __shared__ short Ah[128 * LSTR], Al[128 * LSTR], Bh[128 * LSTR], Bl[128 * LSTR];
  int tid = threadIdx.x;
  int n0 = blockIdx.x * 128, m0 = blockIdx.y * 128;
  int K2 = 2 * K;
  int w = tid >> 6, lane = tid & 63;
  int wm = w >> 1, wn = w & 1;
  int quad = lane >> 4, l16 = lane & 15;

  ffrag acc[4][4];
#pragma unroll
  for (int i = 0; i < 4; ++i)
#pragma unroll
    for (int j = 0; j < 4; ++j) acc[i][j] = (ffrag)(0.f);

  // staging assignments (constant over k-loop)
  int sr0 = tid >> 2, sc0 = (tid & 3) * 8;           // rows 0..63
  const ushort* gA0 = A2 + (size_t)(m0 + sr0) * K2 + sc0;
  const ushort* gA1 = A2 + (size_t)(m0 + sr0 + 64) * K2 + sc0;
  const ushort* gB0 = W2 + (size_t)(n0 + sr0) * K2 + sc0;
  const ushort* gB1 = W2 + (size_t)(n0 + sr0 + 64) * K2 + sc0;
  int ld0 = sr0 * LSTR + sc0, ld1 = (sr0 + 64) * LSTR + sc0;

  for (int k0 = 0; k0 < K; k0 += 32) {
    *(uint4*)&Ah[ld0] = *(const uint4*)(gA0 + k0);
    *(uint4*)&Al[ld0] = *(const uint4*)(gA0 + k0 + K);
    *(uint4*)&Bh[ld0] = *(const uint4*)(gB0 + k0);
    *(uint4*)&Bl[ld0] = *(const uint4*)(gB0 + k0 + K);
    *(uint4*)&Ah[ld1] = *(const uint4*)(gA1 + k0);
    *(uint4*)&Al[ld1] = *(const uint4*)(gA1 + k0 + K);
    *(uint4*)&Bh[ld1] = *(const uint4*)(gB1 + k0);
    *(uint4*)&Bl[ld1] = *(const uint4*)(gB1 + k0 + K);
    __syncthreads();

    bfrag ah[4], al[4], bh[4], bl[4];
#pragma unroll
    for (int i = 0; i < 4; ++i) {
      int ra = (wm * 64 + i * 16 + l16) * LSTR + quad * 8;
      ah[i] = *(const bfrag*)&Ah[ra];
      al[i] = *(const bfrag*)&Al[ra];
      int rb = (wn * 64 + i * 16 + l16) * LSTR + quad * 8;
      bh[i] = *(const bfrag*)&Bh[rb];
      bl[i] = *(const bfrag*)&Bl[rb];
    }
#pragma unroll
    for (int i = 0; i < 4; ++i)
#pragma unroll
      for (int j = 0; j < 4; ++j) {
        acc[i][j] = __builtin_amdgcn_mfma_f32_16x16x32_bf16(ah[i], bh[j], acc[i][j], 0, 0, 0);
        acc[i][j] = __builtin_amdgcn_mfma_f32_16x16x32_bf16(ah[i], bl[j], acc[i][j], 0, 0, 0);
        acc[i][j] = __builtin_amdgcn_mfma_f32_16x16x32_bf16(al[i], bh[j], acc[i][j], 0, 0, 0);
      }
    __syncthreads();
  }

  // epilogue: C layout col = lane&15, row = quad*4 + reg
#pragma unroll
  for (int j = 0; j < 4; ++j) {
    int col = n0 + wn * 64 + j * 16 + l16;
    float bcol = bias[col];
#pragma unroll
    for (int i = 0; i < 4; ++i) {
      int rowb = m0 + wm * 64 + i * 16 + quad * 4;
#pragma unroll
      for (int r = 0; r < 4; ++r) {
        int row = rowb + r;
        float vv = acc[i][j][r] + bcol;
        if (EPI == 1) vv = 0.5f * vv * (1.0f + erff(vv * 0.7071067811865475f));
        if (EPI == 2) vv += R[(size_t)row * N + col];
        Cout[(size_t)row * N + col] = vv;
      }
    }
  }
}

// ---------------- top-k (k=20) + softmax weights ----------------
__global__ __launch_bounds__(256) void k_topk(const float* __restrict__ corrb,
                                              float* __restrict__ wts,
                                              int* __restrict__ idxs) {
  int b = blockIdx.x, tid = threadIdx.x;
  __shared__ float vals[CT];
  __shared__ float bestv[256];
  __shared__ int besti[256];
  __shared__ float selv[CTOPK];
  __shared__ int seli[CTOPK];
  for (int i = tid; i < CT; i += 256) vals[i] = corrb[(size_t)b * CT + i];
  __syncthreads();
  for (int k = 0; k < CTOPK; ++k) {
    float bv = -INFINITY;
    int bi = CT;
    for (int i = tid; i < CT; i += 256) {
      float v = vals[i];
      if (v > bv || (v == bv && i < bi)) { bv = v; bi = i; }
    }
    bestv[tid] = bv;
    besti[tid] = bi;
    __syncthreads();
    for (int off = 128; off > 0; off >>= 1) {
      if (tid < off) {
        float ov = bestv[tid + off];
        int oi = besti[tid + off];
        if (ov > bestv[tid] || (ov == bestv[tid] && oi < besti[tid])) {
          bestv[tid] = ov;
          besti[tid] = oi;
        }
      }
      __syncthreads();
    }
    if (tid == 0) {
      selv[k] = bestv[0];
      seli[k] = besti[0];
      vals[besti[0]] = -INFINITY;
    }
    __syncthreads();
  }
  if (tid == 0) {
    float mx = selv[0], sum = 0.f, e[CTOPK];
    for (int k = 0; k < CTOPK; ++k) {
      e[k] = expf(selv[k] - mx);
      sum += e[k];
    }
    float inv = 1.0f / sum;
    for (int k = 0; k < CTOPK; ++k) {
      wts[b * CTOPK + k] = e[k] * inv;
      idxs[b * CTOPK + k] = seli[k];
    }
  }
}

// ---------------- delay aggregation ----------------
__global__ __launch_bounds__(128) void k_agg(const float* __restrict__ V,
                                             const float* __restrict__ wts,
                                             const int* __restrict__ idxs,
                                             float* __restrict__ out) {
  int row = blockIdx.x;
  int b = row >> 10, t = row & 1023;
  int d0 = threadIdx.x * 4;
  const float* Vb = V + (size_t)b * CT * CD;
  float4 acc = {0.f, 0.f, 0.f, 0.f};
#pragma unroll
  for (int k = 0; k < CTOPK; ++k) {
    float w = wts[b * CTOPK + k];
    int r = t + idxs[b * CTOPK + k];
    if (r >= CT) r -= CT;
    float4 v = *(const float4*)(Vb + (size_t)r * CD + d0);
    acc.x += w * v.x;
    acc.y += w * v.y;
    acc.z += w * v.z;
    acc.w += w * v.w;
  }
  *(float4*)(out + (size_t)row * CD + d0) = acc;
}

// ---------------- LayerNorm (optional residual add) ----------------
template <int ADD>
__global__ __launch_bounds__(128) void k_ln(const float* __restrict__ X,
                                            const float* __restrict__ Rr,
                                            const float* __restrict__ g,
                                            const float* __restrict__ beta,
                                            float* __restrict__ out) {
  int row = blockIdx.x, tid = threadIdx.x;
  int d0 = tid * 4;
  float4 v = *(const float4*)(X + (size_t)row * CD + d0);
  if (ADD) {
    float4 r = *(const float4*)(Rr + (size_t)row * CD + d0);
    v.x += r.x; v.y += r.y; v.z += r.z; v.w += r.w;
  }
  float s1 = v.x + v.y + v.z + v.w;
  float s2 = v.x * v.x + v.y * v.y + v.z * v.z + v.w * v.w;
  for (int off = 32; off > 0; off >>= 1) {
    s1 += __shfl_down(s1, off);
    s2 += __shfl_down(s2, off);
  }
  __shared__ float ws1[2], ws2[2], mv[2];
  int wid = tid >> 6, lane = tid & 63;
  if (lane == 0) { ws1[wid] = s1; ws2[wid] = s2; }
  __syncthreads();
  if (tid == 0) {
    float S1 = ws1[0] + ws1[1], S2 = ws2[0] + ws2[1];
    float mu = S1 * (1.0f / CD);
    float var = S2 * (1.0f / CD) - mu * mu;
    mv[0] = mu;
    mv[1] = 1.0f / sqrtf(var + CEPS);
  }
  __syncthreads();
  float mu = mv[0], ri = mv[1];
  float4 gg = *(const float4*)(g + d0);
  float4 bb = *(const float4*)(beta + d0);
  float4 o;
  o.x = (v.x - mu) * ri * gg.x + bb.x;
  o.y = (v.y - mu) * ri * gg.y + bb.y;
  o.z = (v.z - mu) * ri * gg.z + bb.z;
  o.w = (v.w - mu) * ri * gg.w + bb.w;
  *(float4*)(out + (size_t)row * CD + d0) = o;
}

// ---------------- series decomposition: x - movavg25(x, edge-replicated) ------------
__global__ __launch_bounds__(128) void k_decomp(const float* __restrict__ X,
                                                float* __restrict__ out) {
  int row = blockIdx.x;
  int b = row >> 10, t = row & 1023;
  int d0 = threadIdx.x * 4;
  const float* xb = X + (size_t)b * CT * CD + d0;
  float4 s = {0.f, 0.f, 0.f, 0.f};
#pragma unroll
  for (int j = -12; j <= 12; ++j) {
    int tt = t + j;
    tt = tt < 0 ? 0 : (tt > CT - 1 ? CT - 1 : tt);
    float4 v = *(const float4*)(xb + (size_t)tt * CD);
    s.x += v.x; s.y += v.y; s.z += v.z; s.w += v.w;
  }
  float4 xv = *(const float4*)(xb + (size_t)t * CD);
  const float inv = 1.0f / 25.0f;
  float4 o = {xv.x - s.x * inv, xv.y - s.y * inv, xv.z - s.z * inv, xv.w - s.w * inv};
  *(float4*)(out + (size_t)row * CD + d0) = o;
}

// ---------------- time mean ----------------
__global__ __launch_bounds__(512) void k_meant(const float* __restrict__ X,
                                               float* __restrict__ feat) {
  int b = blockIdx.x, d = threadIdx.x;
  const float* xb = X + (size_t)b * CT * CD + d;
  float acc = 0.f;
  for (int t = 0; t < CT; ++t) acc += xb[(size_t)t * CD];
  feat[b * CD + d] = acc * (1.0f / CT);
}

// ---------------- classification head ----------------
__global__ __launch_bounds__(256) void k_head(const float* __restrict__ feat,
                                              const float* __restrict__ w1,
                                              const float* __restrict__ b1,
                                              const float* __restrict__ w2,
                                              const float* __restrict__ b2,
                                              float* __restrict__ out) {
  int b = blockIdx.x, tid = threadIdx.x;
  __shared__ float f[CD];
  __shared__ float hid[CFCH];
  for (int i = tid; i < CD; i += 256) f[i] = feat[b * CD + i];
  __syncthreads();
  float acc = b1[tid];
  for (int d = 0; d < CD; ++d) acc += f[d] * w1[d * CFCH + tid];
  hid[tid] = fmaxf(acc, 0.f);
  __syncthreads();
  if (tid < CNC) {
    float acc2 = b2[tid];
    for (int j = 0; j < CFCH; ++j) acc2 += hid[j] * w2[j * CNC + tid];
    out[b * CNC + tid] = acc2;
  }
}

// =====================================================================================
extern "C" void kernel_launch(void* const* d_in, const int* in_sizes, int n_in,
                              void* d_out, int out_size, void* d_ws, size_t ws_size,
                              hipStream_t stream) {
  const float* x = (const float*)d_in[0];
  const float* emb_w = (const float*)d_in[1];
  const float* emb_g = (const float*)d_in[2];
  const float* emb_b = (const float*)d_in[3];
  const float* attn_w = (const float*)d_in[4];
  const float* attn_b = (const float*)d_in[5];
  const float* ln_g = (const float*)d_in[6];
  const float* ln_bb = (const float*)d_in[7];
  const float* fc1_w = (const float*)d_in[8];
  const float* fc1_b = (const float*)d_in[9];
  const float* fc2_w = (const float*)d_in[10];
  const float* fc2_b = (const float*)d_in[11];
  const float* hw1 = (const float*)d_in[12];
  const float* hb1 = (const float*)d_in[13];
  const float* hw2 = (const float*)d_in[14];
  const float* hb2 = (const float*)d_in[15];
  float* outp = (float*)d_out;

  // per-layer W2 region (ushorts): Wv2(512x1024) Wo2(512x1024) W12(2048x1024) W22(512x4096)
  const size_t LW = 524288ULL + 524288ULL + 2097152ULL + 2097152ULL;  // 5,242,880
  const size_t W2TOT = CL * LW;  // ushorts

  // pick largest Bc that fits
  const size_t FIXED_B = W2TOT * 2                    // W2 bf16
                         + (size_t)CT * CD * 4        // postab
                         + 2 * (size_t)CB * CCH * 4   // sc,lg
                         + (size_t)CB * CT * 4        // corrb
                         + 2 * (size_t)CB * CTOPK * 4 // wts,idxs
                         + (size_t)CB * CD * 4        // feat
                         + 4096;                      // alignment slack
  int Bc = CB;
  while (Bc > 1) {
    size_t need = (size_t)Bc * (3ULL * CT * CD * 4 + 2ULL * CT * CT / 512 * 1024  /*A2+B2 bytes: 4MB/b*/)
                  + FIXED_B;
    // A2+B2 bytes per batch = 2 * (1024 rows * 1024 ushort * 2B) = 4 MiB
    need = (size_t)Bc * (3ULL * CT * CD * 4 + 4ULL * 1024 * 1024) + FIXED_B;
    if (need <= ws_size) break;
    Bc >>= 1;
  }
  const size_t CHF = (size_t)Bc * CT * CD;  // floats per fp32 buffer

  char* wsp = (char*)d_ws;
  float* P0 = (float*)wsp;                     wsp += CHF * 4;
  float* P1 = (float*)wsp;                     wsp += CHF * 4;
  float* P2 = (float*)wsp;                     wsp += CHF * 4;
  ushort* A2 = (ushort*)wsp;                   wsp += (size_t)Bc * CT * 1024 * 2;
  ushort* B2 = (ushort*)wsp;                   wsp += (size_t)Bc * CT * 1024 * 2;
  float* Sbuf = (float*)A2;  // aliases A2+B2 (4*Bc MiB) during the corr phase
  ushort* W2b = (ushort*)wsp;                  wsp += W2TOT * 2;
  float* postab = (float*)wsp;                 wsp += (size_t)CT * CD * 4;
  float* scb = (float*)wsp;                    wsp += (size_t)CB * CCH * 4;
  float* lgb = (float*)wsp;                    wsp += (size_t)CB * CCH * 4;
  float* corrb = (float*)wsp;                  wsp += (size_t)CB * CT * 4;
  float* wtb = (float*)wsp;                    wsp += (size_t)CB * CTOPK * 4;
  int* idb = (int*)wsp;                        wsp += (size_t)CB * CTOPK * 4;
  float* featb = (float*)wsp;

  // ---- convert weights (V,O,FC1,FC2) to transposed bf16-split, once per call ----
  for (int l = 0; l < CL; ++l) {
    const float* Wv = attn_w + ((size_t)(l * 4 + 2)) * CD * CD;
    const float* Wo = attn_w + ((size_t)(l * 4 + 3)) * CD * CD;
    const float* W1 = fc1_w + (size_t)l * CD * CFFN;
    const float* Wf2 = fc2_w + (size_t)l * CFFN * CD;
    ushort* wv2 = W2b + l * LW;
    ushort* wo2 = wv2 + 524288;
    ushort* w12 = wo2 + 524288;
    ushort* w22 = w12 + 2097152;
    k_cvtw<<<dim3(CD / 32, CD / 32), 256, 0, stream>>>(Wv, wv2, CD, CD);
    k_cvtw<<<dim3(CD / 32, CD / 32), 256, 0, stream>>>(Wo, wo2, CD, CD);
    k_cvtw<<<dim3(CFFN / 32, CD / 32), 256, 0, stream>>>(W1, w12, CD, CFFN);
    k_cvtw<<<dim3(CD / 32, CFFN / 32), 256, 0, stream>>>(Wf2, w22, CFFN, CD);
  }

  k_scale<<<CB, 256, 0, stream>>>(x, scb, lgb);
  k_postab<<<CT, 512, 0, stream>>>(postab);

  for (int b0 = 0; b0 < CB; b0 += Bc) {
    const int Mc = Bc * CT;
    const int MCH = Mc / 4;

    k_embed<<<Mc, 128, 0, stream>>>(x + (size_t)b0 * CT * CCH, scb + b0 * CCH,
                                    lgb + b0 * CCH, emb_w, postab, emb_g, emb_b, P0);

    float* h = P0;
    float* bufA = P1;
    float* bufB = P2;
    for (int l = 0; l < CL; ++l) {
      const float* Wq = attn_w + ((size_t)(l * 4 + 0)) * CD * CD;
      const float* Wk = attn_w + ((size_t)(l * 4 + 1)) * CD * CD;
      const float* bq = attn_b + (size_t)(l * 4 + 0) * CD;
      const float* bk = attn_b + (size_t)(l * 4 + 1) * CD;
      const float* bv = attn_b + (size_t)(l * 4 + 2) * CD;
      const float* bo = attn_b + (size_t)(l * 4 + 3) * CD;
      const float* g0 = ln_g + (size_t)(l * 2 + 0) * CD;
      const float* be0 = ln_bb + (size_t)(l * 2 + 0) * CD;
      const float* g1 = ln_g + (size_t)(l * 2 + 1) * CD;
      const float* be1 = ln_bb + (size_t)(l * 2 + 1) * CD;
      const float* B1 = fc1_b + (size_t)l * CFFN;
      const float* B2f = fc2_b + (size_t)l * CD;
      const ushort* wv2 = W2b + l * LW;
      const ushort* wo2 = wv2 + 524288;
      const ushort* w12 = wo2 + 524288;
      const ushort* w22 = w12 + 2097152;

      dim3 gD(CD / BN, Mc / BM);
      // Q, K projections — exact fp32 path feeding top-k (unchanged numerics)
      k_gemm<0><<<gD, 256, 0, stream>>>(h, Wq, bq, nullptr, bufA, Mc, CD, CD);
      k_gemm<0><<<gD, 256, 0, stream>>>(h, Wk, bk, nullptr, bufB, Mc, CD, CD);
      // S = Q K^T per batch, then diagonal fold -> corr, then top-k
      k_gemmnt<<<dim3(CT / BN, CT / BM, Bc), 256, 0, stream>>>(bufA, bufB, Sbuf);
      k_fold<<<dim3(CT / 64, Bc), 256, 0, stream>>>(Sbuf, corrb);
      k_topk<<<Bc, 256, 0, stream>>>(corrb, wtb, idb);
      // V projection (bf16-split MFMA), aggregation, O projection
      k_cvta<<<(unsigned)(((size_t)Mc * CD) / 1024), 256, 0, stream>>>(h, A2, 9);
      k_gemm2<0><<<dim3(CD / 128, Mc / 128), 256, 0, stream>>>(A2, wv2, bv, nullptr,
                                                               bufA, Mc, CD, CD);
      k_agg<<<Mc, 128, 0, stream>>>(bufA, wtb, idb, bufB);
      k_cvta<<<(unsigned)(((size_t)Mc * CD) / 1024), 256, 0, stream>>>(bufB, A2, 9);
      k_gemm2<0><<<dim3(CD / 128, Mc / 128), 256, 0, stream>>>(A2, wo2, bo, nullptr,
                                                               bufA, Mc, CD, CD);
      // residual + LN, decomp
      k_ln<1><<<Mc, 128, 0, stream>>>(h, bufA, g0, be0, h);
      k_decomp<<<Mc, 128, 0, stream>>>(h, bufB);
      // FFN: in2 = split(bufB); per M-chunk: f=gelu(in2*W1), h = f*W2 + b + in
      k_cvta<<<(unsigned)(((size_t)Mc * CD) / 1024), 256, 0, stream>>>(bufB, A2, 9);
      for (int ch = 0; ch < 4; ++ch) {
        const ushort* in2 = A2 + (size_t)ch * MCH * 1024;
        const float* res = bufB + (size_t)ch * MCH * CD;
        float* outc = h + (size_t)ch * MCH * CD;
        k_gemm2<1><<<dim3(CFFN / 128, MCH / 128), 256, 0, stream>>>(
            in2, w12, B1, nullptr, bufA, MCH, CFFN, CD);
        k_cvta<<<(unsigned)(((size_t)MCH * CFFN) / 1024), 256, 0, stream>>>(bufA, B2, 11);
        k_gemm2<2><<<dim3(CD / 128, MCH / 128), 256, 0, stream>>>(
            B2, w22, B2f, res, outc, MCH, CD, CFFN);
      }
      k_ln<0><<<Mc, 128, 0, stream>>>(h, nullptr, g1, be1, h);
      k_decomp<<<Mc, 128, 0, stream>>>(h, bufA);
      float* t0 = h;
      h = bufA;
      bufA = bufB;
      bufB = t0;
    }

    k_meant<<<Bc, 512, 0, stream>>>(h, featb);
    k_head<<<Bc, 256, 0, stream>>>(featb, hw1, hb1, hw2, hb2, outp + (size_t)b0 * CNC);
  }
}

// Round 4
// 8290.717 us; speedup vs baseline: 1.9257x; 1.2908x over previous
//
#include <hip/hip_runtime.h>
#include <math.h>

#define CB 64      // batch
#define CT 1024    // time
#define CCH 12     // channels
#define CD 512     // d_model
#define CL 2       // layers
#define CFFN 2048
#define CFCH 256
#define CNC 5
#define CTOPK 20
#define CEPS 1e-5f

typedef __attribute__((ext_vector_type(8))) short bfrag;
typedef __attribute__((ext_vector_type(4))) float ffrag;

__device__ inline ushort bf16r(float f) {
  unsigned u = __float_as_uint(f);
  unsigned r = (u + 0x7FFFu + ((u >> 16) & 1u)) >> 16;
  return (ushort)r;
}
__device__ inline float bf16f(ushort h) { return __uint_as_float(((unsigned)h) << 16); }

// ---------------- mean-abs scaler ----------------
__global__ __launch_bounds__(256) void k_scale(const float* __restrict__ x,
                                               float* __restrict__ sc,
                                               float* __restrict__ lg) {
  int b = blockIdx.x, tid = threadIdx.x;
  float acc[CCH];
#pragma unroll
  for (int c = 0; c < CCH; ++c) acc[c] = 0.f;
  const float* xb = x + (size_t)b * CT * CCH;
  for (int t = tid; t < CT; t += 256) {
    const float* row = xb + t * CCH;
#pragma unroll
    for (int c = 0; c < CCH; ++c) acc[c] += fabsf(row[c]);
  }
  __shared__ float red[256][CCH];
#pragma unroll
  for (int c = 0; c < CCH; ++c) red[tid][c] = acc[c];
  __syncthreads();
  for (int off = 128; off > 0; off >>= 1) {
    if (tid < off) {
#pragma unroll
      for (int c = 0; c < CCH; ++c) red[tid][c] += red[tid + off][c];
    }
    __syncthreads();
  }
  if (tid < CCH) {
    float s = fmaxf(red[0][tid] * (1.0f / CT), 1e-10f);
    sc[b * CCH + tid] = s;
    lg[b * CCH + tid] = logf(s);
  }
}

// ---------------- sinusoidal position table (f64, matches np) ----------------
__global__ __launch_bounds__(512) void k_postab(float* __restrict__ pos) {
  int t = blockIdx.x;
  int d = threadIdx.x;
  double v;
  if (d < 256) {
    double w = pow(10000.0, -((double)d) / 256.0);
    v = sin((double)t * w);
  } else {
    double w = pow(10000.0, -((double)(d - 256)) / 256.0);
    v = cos((double)t * w);
  }
  pos[(size_t)t * CD + d] = (float)v;
}

// ---------------- embedding + LN fused; writes fp32 h AND split-bf16 h2 -------------
__global__ __launch_bounds__(128) void k_embed(const float* __restrict__ x,
                                               const float* __restrict__ sc,
                                               const float* __restrict__ lg,
                                               const float* __restrict__ W,
                                               const float* __restrict__ postab,
                                               const float* __restrict__ g,
                                               const float* __restrict__ beta,
                                               float* __restrict__ h,
                                               ushort* __restrict__ h2) {
  int row = blockIdx.x;  // local: b*T + t
  int b = row >> 10, t = row & 1023;
  int tid = threadIdx.x;
  __shared__ float xs[CCH], ls[CCH];
  if (tid < CCH) {
    float s = sc[b * CCH + tid];
    xs[tid] = x[(size_t)row * CCH + tid] / s;
    ls[tid] = lg[b * CCH + tid];
  }
  __syncthreads();
  int d0 = tid * 4;
  float4 p = *(const float4*)(postab + (size_t)t * CD + d0);
  float v0 = p.x, v1 = p.y, v2 = p.z, v3 = p.w;
#pragma unroll
  for (int c = 0; c < CCH; ++c) {
    float xc = xs[c], lc = ls[c];
    float4 w0 = *(const float4*)(W + (size_t)c * CD + d0);
    float4 w1 = *(const float4*)(W + (size_t)(24 + c) * CD + d0);
    v0 += xc * w0.x + lc * w1.x;
    v1 += xc * w0.y + lc * w1.y;
    v2 += xc * w0.z + lc * w1.z;
    v3 += xc * w0.w + lc * w1.w;
  }
  float s1 = v0 + v1 + v2 + v3;
  float s2 = v0 * v0 + v1 * v1 + v2 * v2 + v3 * v3;
  for (int off = 32; off > 0; off >>= 1) {
    s1 += __shfl_down(s1, off);
    s2 += __shfl_down(s2, off);
  }
  __shared__ float ws1[2], ws2[2], mv[2];
  int wid = tid >> 6, lane = tid & 63;
  if (lane == 0) { ws1[wid] = s1; ws2[wid] = s2; }
  __syncthreads();
  if (tid == 0) {
    float S1 = ws1[0] + ws1[1], S2 = ws2[0] + ws2[1];
    float mu = S1 * (1.0f / CD);
    float var = S2 * (1.0f / CD) - mu * mu;
    mv[0] = mu;
    mv[1] = 1.0f / sqrtf(var + CEPS);
  }
  __syncthreads();
  float mu = mv[0], ri = mv[1];
  float4 gg = *(const float4*)(g + d0);
  float4 bb = *(const float4*)(beta + d0);
  float4 o;
  o.x = (v0 - mu) * ri * gg.x + bb.x;
  o.y = (v1 - mu) * ri * gg.y + bb.y;
  o.z = (v2 - mu) * ri * gg.z + bb.z;
  o.w = (v3 - mu) * ri * gg.w + bb.w;
  *(float4*)(h + (size_t)row * CD + d0) = o;
  ushort h0 = bf16r(o.x), h1 = bf16r(o.y), h2v = bf16r(o.z), h3 = bf16r(o.w);
  ushort l0 = bf16r(o.x - bf16f(h0)), l1 = bf16r(o.y - bf16f(h1));
  ushort l2 = bf16r(o.z - bf16f(h2v)), l3 = bf16r(o.w - bf16f(h3));
  ushort4 hv = {h0, h1, h2v, h3};
  ushort4 lv = {l0, l1, l2, l3};
  *(ushort4*)(h2 + (size_t)row * 1024 + d0) = hv;
  *(ushort4*)(h2 + (size_t)row * 1024 + 512 + d0) = lv;
}

// ---------------- weight convert+transpose: W[K][N] fp32 -> W2[N][2K] bf16 hi|lo ----
__global__ __launch_bounds__(256) void k_cvtw(const float* __restrict__ W,
                                              ushort* __restrict__ W2,
                                              int K, int N) {
  __shared__ float tile[32][33];
  int tx = threadIdx.x & 31, ty = threadIdx.x >> 5;  // ty 0..7
  int n0 = blockIdx.x * 32, k0 = blockIdx.y * 32;
#pragma unroll
  for (int r = 0; r < 4; ++r)
    tile[ty * 4 + r][tx] = W[(size_t)(k0 + ty * 4 + r) * N + n0 + tx];
  __syncthreads();
#pragma unroll
  for (int r = 0; r < 4; ++r) {
    int nl = ty * 4 + r, kl = tx;
    float f = tile[kl][nl];
    ushort hi = bf16r(f);
    ushort lo = bf16r(f - bf16f(hi));
    size_t base = (size_t)(n0 + nl) * (size_t)(2 * K) + k0 + kl;
    W2[base] = hi;
    W2[base + K] = lo;
  }
}

// ---------------- bf16-split MFMA GEMM ----------------------------------------------
// A2: [M][2K] hi|lo, W2: [N][2K] hi|lo (both k-contiguous).
// EPI: 0=bias->fp32  1=bias+GELU->split  2=bias+residual->fp32  3=raw->fp32(S)
//      4=bias->split
#define LSTR 40  // LDS row stride in bf16 elems (16B aligned; 20*row%32 -> 2-way max)
template <int EPI, int BNT>
__global__ __launch_bounds__(256) void k_gemm2(const ushort* __restrict__ A2,
                                               const ushort* __restrict__ W2,
                                               const float* __restrict__ bias,
                                               const float* __restrict__ R,
                                               float* __restrict__ Cout,
                                               ushort* __restrict__ Cs,
                                               int M, int N, int K,
                                               size_t aBatch, size_t wBatch,
                                               size_t cBatch) {
  constexpr int MT = (BNT == 128) ? 4 : 2;  // 16-row tiles per wave (m)
  __shared__ short Ah[128 * LSTR], Al[128 * LSTR];
  __shared__ short Bh[BNT * LSTR], Bl[BNT * LSTR];
  int tid = threadIdx.x;
  int n0 = blockIdx.x * BNT, m0 = blockIdx.y * 128;
  int K2 = 2 * K;
  int w = tid >> 6, lane = tid & 63;
  int wm = (BNT == 128) ? (w >> 1) : w;
  int wn = (BNT == 128) ? (w & 1) : 0;
  int mOff = wm * MT * 16, nOff = wn * 64;
  int quad = lane >> 4, l16 = lane & 15;

  const ushort* Az = A2 + (size_t)blockIdx.z * aBatch;
  const ushort* Wz = W2 + (size_t)blockIdx.z * wBatch;

  ffrag acc[MT][4];
#pragma unroll
  for (int i = 0; i < MT; ++i)
#pragma unroll
    for (int j = 0; j < 4; ++j) acc[i][j] = (ffrag)(0.f);

  int sr = tid >> 2, sc = (tid & 3) * 8;
  const ushort* gA0 = Az + (size_t)(m0 + sr) * K2 + sc;
  const ushort* gA1 = Az + (size_t)(m0 + sr + 64) * K2 + sc;
  const ushort* gB0 = Wz + (size_t)(n0 + sr) * K2 + sc;
  const ushort* gB1 = Wz + (size_t)(n0 + ((BNT == 128) ? sr + 64 : sr)) * K2 + sc;
  int ld0 = sr * LSTR + sc, ld1 = (sr + 64) * LSTR + sc;

  for (int k0 = 0; k0 < K; k0 += 32) {
    *(uint4*)&Ah[ld0] = *(const uint4*)(gA0 + k0);
    *(uint4*)&Al[ld0] = *(const uint4*)(gA0 + k0 + K);
    *(uint4*)&Ah[ld1] = *(const uint4*)(gA1 + k0);
    *(uint4*)&Al[ld1] = *(const uint4*)(gA1 + k0 + K);
    *(uint4*)&Bh[ld0] = *(const uint4*)(gB0 + k0);
    *(uint4*)&Bl[ld0] = *(const uint4*)(gB0 + k0 + K);
    if (BNT == 128) {
      *(uint4*)&Bh[ld1] = *(const uint4*)(gB1 + k0);
      *(uint4*)&Bl[ld1] = *(const uint4*)(gB1 + k0 + K);
    }
    __syncthreads();

    bfrag ah[MT], al[MT], bh[4], bl[4];
#pragma unroll
    for (int i = 0; i < MT; ++i) {
      int ra = (mOff + i * 16 + l16) * LSTR + quad * 8;
      ah[i] = *(const bfrag*)&Ah[ra];
      al[i] = *(const bfrag*)&Al[ra];
    }
#pragma unroll
    for (int j = 0; j < 4; ++j) {
      int rb = (nOff + j * 16 + l16) * LSTR + quad * 8;
      bh[j] = *(const bfrag*)&Bh[rb];
      bl[j] = *(const bfrag*)&Bl[rb];
    }
#pragma unroll
    for (int i = 0; i < MT; ++i)
#pragma unroll
      for (int j = 0; j < 4; ++j) {
        acc[i][j] = __builtin_amdgcn_mfma_f32_16x16x32_bf16(ah[i], bh[j], acc[i][j], 0, 0, 0);
        acc[i][j] = __builtin_amdgcn_mfma_f32_16x16x32_bf16(ah[i], bl[j], acc[i][j], 0, 0, 0);
        acc[i][j] = __builtin_amdgcn_mfma_f32_16x16x32_bf16(al[i], bh[j], acc[i][j], 0, 0, 0);
      }
    __syncthreads();
  }

  // epilogue: C tile layout col = lane&15, row = quad*4 + reg
  size_t cb = (size_t)blockIdx.z * cBatch;
#pragma unroll
  for (int j = 0; j < 4; ++j) {
    int col = n0 + nOff + j * 16 + l16;
    float bcol = (EPI == 3) ? 0.f : bias[col];
#pragma unroll
    for (int i = 0; i < MT; ++i) {
      int rowb = m0 + mOff + i * 16 + quad * 4;
#pragma unroll
      for (int r = 0; r < 4; ++r) {
        int row = rowb + r;
        float vv = acc[i][j][r] + bcol;
        if (EPI == 1) vv = 0.5f * vv * (1.0f + erff(vv * 0.7071067811865475f));
        if (EPI == 2) vv += R[(size_t)row * N + col];
        if (EPI == 1 || EPI == 4) {
          ushort hi = bf16r(vv);
          ushort lo = bf16r(vv - bf16f(hi));
          Cs[(size_t)row * (2 * N) + col] = hi;
          Cs[(size_t)row * (2 * N) + N + col] = lo;
        } else {
          Cout[cb + (size_t)row * N + col] = vv;
        }
      }
    }
  }
}

// ---------------- diagonal fold: corr[b,tau] = (1/512) sum_j S[b,(tau+j)%T, j] ------
__global__ __launch_bounds__(256) void k_fold(const float* __restrict__ S,
                                              float* __restrict__ corrb) {
  int b = blockIdx.y, tau0 = blockIdx.x * 64;
  int tid = threadIdx.x;
  int tl = tid & 63, p = tid >> 6;
  __shared__ float Sb[128][65];
  __shared__ float red[4][64];
  const float* Sbase = S + (size_t)b * CT * CT;
  float acc = 0.f;
  for (int jc = 0; jc < 16; ++jc) {
    int jbase = jc * 64;
    __syncthreads();
    for (int rnd = 0; rnd < 8; ++rnd) {
      int rr = rnd * 16 + (tid >> 4);
      int c4 = (tid & 15) * 4;
      int gi = (tau0 + jbase + rr) & (CT - 1);
      float4 v = *(const float4*)(Sbase + (size_t)gi * CT + jbase + c4);
      Sb[rr][c4 + 0] = v.x;
      Sb[rr][c4 + 1] = v.y;
      Sb[rr][c4 + 2] = v.z;
      Sb[rr][c4 + 3] = v.w;
    }
    __syncthreads();
#pragma unroll
    for (int q = 0; q < 16; ++q) {
      int jl = p * 16 + q;
      acc += Sb[tl + jl][jl];
    }
  }
  red[p][tl] = acc;
  __syncthreads();
  if (tid < 64) {
    float s = red[0][tid] + red[1][tid] + red[2][tid] + red[3][tid];
    corrb[(size_t)b * CT + tau0 + tid] = s * (1.0f / 512.0f);
  }
}

// ---------------- top-k (k=20) + softmax, 1024 threads (1/τ) ----------------
__global__ __launch_bounds__(1024) void k_topk(const float* __restrict__ corrb,
                                               float* __restrict__ wts,
                                               int* __restrict__ idxs) {
  int b = blockIdx.x, tid = threadIdx.x;
  float cur = corrb[(size_t)b * CT + tid];
  __shared__ float swv[16];
  __shared__ int swi[16];
  __shared__ float selv[CTOPK];
  __shared__ int seli[CTOPK];
  int wid = tid >> 6, lane = tid & 63;
  for (int k = 0; k < CTOPK; ++k) {
    float bv = cur;
    int bi = tid;
#pragma unroll
    for (int off = 32; off > 0; off >>= 1) {
      float ov = __shfl_down(bv, off);
      int oi = __shfl_down(bi, off);
      if (ov > bv || (ov == bv && oi < bi)) { bv = ov; bi = oi; }
    }
    if (lane == 0) { swv[wid] = bv; swi[wid] = bi; }
    __syncthreads();
    if (tid == 0) {
      float mv = swv[0];
      int mi = swi[0];
      for (int q = 1; q < 16; ++q) {
        if (swv[q] > mv || (swv[q] == mv && swi[q] < mi)) { mv = swv[q]; mi = swi[q]; }
      }
      selv[k] = mv;
      seli[k] = mi;
    }
    __syncthreads();
    if (tid == seli[k]) cur = -INFINITY;
    __syncthreads();
  }
  if (tid == 0) {
    float mx = selv[0], sum = 0.f, e[CTOPK];
    for (int k = 0; k < CTOPK; ++k) {
      e[k] = expf(selv[k] - mx);
      sum += e[k];
    }
    float inv = 1.0f / sum;
    for (int k = 0; k < CTOPK; ++k) {
      wts[b * CTOPK + k] = e[k] * inv;
      idxs[b * CTOPK + k] = seli[k];
    }
  }
}

// ---------------- delay aggregation: fp32 V in -> split-bf16 out --------------------
__global__ __launch_bounds__(128) void k_agg(const float* __restrict__ V,
                                             const float* __restrict__ wts,
                                             const int* __restrict__ idxs,
                                             ushort* __restrict__ out2) {
  int row = blockIdx.x;
  int b = row >> 10, t = row & 1023;
  int d0 = threadIdx.x * 4;
  const float* Vb = V + (size_t)b * CT * CD;
  float4 acc = {0.f, 0.f, 0.f, 0.f};
#pragma unroll
  for (int k = 0; k < CTOPK; ++k) {
    float w = wts[b * CTOPK + k];
    int r = t + idxs[b * CTOPK + k];
    if (r >= CT) r -= CT;
    float4 v = *(const float4*)(Vb + (size_t)r * CD + d0);
    acc.x += w * v.x;
    acc.y += w * v.y;
    acc.z += w * v.z;
    acc.w += w * v.w;
  }
  ushort h0 = bf16r(acc.x), h1 = bf16r(acc.y), h2v = bf16r(acc.z), h3 = bf16r(acc.w);
  ushort l0 = bf16r(acc.x - bf16f(h0)), l1 = bf16r(acc.y - bf16f(h1));
  ushort l2 = bf16r(acc.z - bf16f(h2v)), l3 = bf16r(acc.w - bf16f(h3));
  ushort4 hv = {h0, h1, h2v, h3};
  ushort4 lv = {l0, l1, l2, l3};
  *(ushort4*)(out2 + (size_t)row * 1024 + d0) = hv;
  *(ushort4*)(out2 + (size_t)row * 1024 + 512 + d0) = lv;
}

// ---------------- LayerNorm (optional residual add) ----------------
template <int ADD>
__global__ __launch_bounds__(128) void k_ln(const float* __restrict__ X,
                                            const float* __restrict__ Rr,
                                            const float* __restrict__ g,
                                            const float* __restrict__ beta,
                                            float* __restrict__ out) {
  int row = blockIdx.x, tid = threadIdx.x;
  int d0 = tid * 4;
  float4 v = *(const float4*)(X + (size_t)row * CD + d0);
  if (ADD) {
    float4 r = *(const float4*)(Rr + (size_t)row * CD + d0);
    v.x += r.x; v.y += r.y; v.z += r.z; v.w += r.w;
  }
  float s1 = v.x + v.y + v.z + v.w;
  float s2 = v.x * v.x + v.y * v.y + v.z * v.z + v.w * v.w;
  for (int off = 32; off > 0; off >>= 1) {
    s1 += __shfl_down(s1, off);
    s2 += __shfl_down(s2, off);
  }
  __shared__ float ws1[2], ws2[2], mv[2];
  int wid = tid >> 6, lane = tid & 63;
  if (lane == 0) { ws1[wid] = s1; ws2[wid] = s2; }
  __syncthreads();
  if (tid == 0) {
    float S1 = ws1[0] + ws1[1], S2 = ws2[0] + ws2[1];
    float mu = S1 * (1.0f / CD);
    float var = S2 * (1.0f / CD) - mu * mu;
    mv[0] = mu;
    mv[1] = 1.0f / sqrtf(var + CEPS);
  }
  __syncthreads();
  float mu = mv[0], ri = mv[1];
  float4 gg = *(const float4*)(g + d0);
  float4 bb = *(const float4*)(beta + d0);
  float4 o;
  o.x = (v.x - mu) * ri * gg.x + bb.x;
  o.y = (v.y - mu) * ri * gg.y + bb.y;
  o.z = (v.z - mu) * ri * gg.z + bb.z;
  o.w = (v.w - mu) * ri * gg.w + bb.w;
  *(float4*)(out + (size_t)row * CD + d0) = o;
}

// ---------------- series decomp: fp32 out + optional split-bf16 out -----------------
__global__ __launch_bounds__(128) void k_decomp(const float* __restrict__ X,
                                                float* __restrict__ out,
                                                ushort* __restrict__ out2) {
  int row = blockIdx.x;
  int b = row >> 10, t = row & 1023;
  int d0 = threadIdx.x * 4;
  const float* xb = X + (size_t)b * CT * CD + d0;
  float4 s = {0.f, 0.f, 0.f, 0.f};
#pragma unroll
  for (int j = -12; j <= 12; ++j) {
    int tt = t + j;
    tt = tt < 0 ? 0 : (tt > CT - 1 ? CT - 1 : tt);
    float4 v = *(const float4*)(xb + (size_t)tt * CD);
    s.x += v.x; s.y += v.y; s.z += v.z; s.w += v.w;
  }
  float4 xv = *(const float4*)(xb + (size_t)t * CD);
  const float inv = 1.0f / 25.0f;
  float4 o = {xv.x - s.x * inv, xv.y - s.y * inv, xv.z - s.z * inv, xv.w - s.w * inv};
  *(float4*)(out + (size_t)row * CD + d0) = o;
  ushort h0 = bf16r(o.x), h1 = bf16r(o.y), h2v = bf16r(o.z), h3 = bf16r(o.w);
  ushort l0 = bf16r(o.x - bf16f(h0)), l1 = bf16r(o.y - bf16f(h1));
  ushort l2 = bf16r(o.z - bf16f(h2v)), l3 = bf16r(o.w - bf16f(h3));
  ushort4 hv = {h0, h1, h2v, h3};
  ushort4 lv = {l0, l1, l2, l3};
  *(ushort4*)(out2 + (size_t)row * 1024 + d0) = hv;
  *(ushort4*)(out2 + (size_t)row * 1024 + 512 + d0) = lv;
}

// ---------------- time mean ----------------
__global__ __launch_bounds__(512) void k_meant(const float* __restrict__ X,
                                               float* __restrict__ feat) {
  int b = blockIdx.x, d = threadIdx.x;
  const float* xb = X + (size_t)b * CT * CD + d;
  float acc = 0.f;
  for (int t = 0; t < CT; ++t) acc += xb[(size_t)t * CD];
  feat[b * CD + d] = acc * (1.0f / CT);
}

// ---------------- classification head ----------------
__global__ __launch_bounds__(256) void k_head(const float* __restrict__ feat,
                                              const float* __restrict__ w1,
                                              const float* __restrict__ b1,
                                              const float* __restrict__ w2,
                                              const float* __restrict__ b2,
                                              float* __restrict__ out) {
  int b = blockIdx.x, tid = threadIdx.x;
  __shared__ float f[CD];
  __shared__ float hid[CFCH];
  for (int i = tid; i < CD; i += 256) f[i] = feat[b * CD + i];
  __syncthreads();
  float acc = b1[tid];
  for (int d = 0; d < CD; ++d) acc += f[d] * w1[d * CFCH + tid];
  hid[tid] = fmaxf(acc, 0.f);
  __syncthreads();
  if (tid < CNC) {
    float acc2 = b2[tid];
    for (int j = 0; j < CFCH; ++j) acc2 += hid[j] * w2[j * CNC + tid];
    out[b * CNC + tid] = acc2;
  }
}

// =====================================================================================
extern "C" void kernel_launch(void* const* d_in, const int* in_sizes, int n_in,
                              void* d_out, int out_size, void* d_ws, size_t ws_size,
                              hipStream_t stream) {
  const float* x = (const float*)d_in[0];
  const float* emb_w = (const float*)d_in[1];
  const float* emb_g = (const float*)d_in[2];
  const float* emb_b = (const float*)d_in[3];
  const float* attn_w = (const float*)d_in[4];
  const float* attn_b = (const float*)d_in[5];
  const float* ln_g = (const float*)d_in[6];
  const float* ln_bb = (const float*)d_in[7];
  const float* fc1_w = (const float*)d_in[8];
  const float* fc1_b = (const float*)d_in[9];
  const float* fc2_w = (const float*)d_in[10];
  const float* fc2_b = (const float*)d_in[11];
  const float* hw1 = (const float*)d_in[12];
  const float* hb1 = (const float*)d_in[13];
  const float* hw2 = (const float*)d_in[14];
  const float* hb2 = (const float*)d_in[15];
  float* outp = (float*)d_out;

  // per-layer split weights (ushorts): wq,wk,wv,wo (512x1024 each) + w1 (2048x1024)
  // + w2 (512x4096)
  const size_t WQ = 524288ULL;
  const size_t LW = 4 * WQ + 2097152ULL + 2097152ULL;  // 6,291,456 ushorts
  const size_t W2TOT = CL * LW;

  const size_t FIXED_B = W2TOT * 2                     // split weights
                         + (size_t)CT * CD * 4         // postab
                         + 2 * (size_t)CB * CCH * 4    // sc,lg
                         + (size_t)CB * CT * 4         // corr
                         + 2 * (size_t)CB * CTOPK * 4  // wts,idxs
                         + (size_t)CB * CD * 4         // feat
                         + 4096;
  // per-batch-elem bytes: 3 fp32 P (6MB) + h2/Q2/K2-a2/d2 splits (6MB) + f2 (8MB)
  const size_t PERB = 3ULL * CT * CD * 4 + 3ULL * CT * 1024 * 2 + (size_t)CT * 4096 * 2;
  int Bc = CB;
  while (Bc > 1) {
    if ((size_t)Bc * PERB + FIXED_B <= ws_size) break;
    Bc >>= 1;
  }
  const size_t CHF = (size_t)Bc * CT * CD;  // floats per fp32 buffer

  char* wsp = (char*)d_ws;
  float* P0 = (float*)wsp;   wsp += CHF * 4;
  float* P1 = (float*)wsp;   wsp += CHF * 4;
  float* P2 = (float*)wsp;   wsp += CHF * 4;
  ushort* R0 = (ushort*)wsp; wsp += (size_t)Bc * CT * 1024 * 2;  // h2
  ushort* R1 = (ushort*)wsp; wsp += (size_t)Bc * CT * 1024 * 2;  // Q2 -> a2
  ushort* R2u = (ushort*)wsp; wsp += (size_t)Bc * CT * 1024 * 2; // K2 -> d2
  ushort* RF = (ushort*)wsp; wsp += (size_t)Bc * CT * 4096 * 2;  // f2
  ushort* W2b = (ushort*)wsp; wsp += W2TOT * 2;
  float* postab = (float*)wsp; wsp += (size_t)CT * CD * 4;
  float* scb = (float*)wsp;    wsp += (size_t)CB * CCH * 4;
  float* lgb = (float*)wsp;    wsp += (size_t)CB * CCH * 4;
  float* corrb = (float*)wsp;  wsp += (size_t)CB * CT * 4;
  float* wtb = (float*)wsp;    wsp += (size_t)CB * CTOPK * 4;
  int* idb = (int*)wsp;        wsp += (size_t)CB * CTOPK * 4;
  float* featb = (float*)wsp;

  // ---- split-convert all six weight matrices per layer, once per call ----
  for (int l = 0; l < CL; ++l) {
    ushort* wq2 = W2b + l * LW;
    ushort* wk2 = wq2 + WQ;
    ushort* wv2 = wk2 + WQ;
    ushort* wo2 = wv2 + WQ;
    ushort* w12 = wo2 + WQ;
    ushort* w22 = w12 + 2097152;
    for (int m = 0; m < 4; ++m)
      k_cvtw<<<dim3(CD / 32, CD / 32), 256, 0, stream>>>(
          attn_w + ((size_t)(l * 4 + m)) * CD * CD, wq2 + m * WQ, CD, CD);
    k_cvtw<<<dim3(CFFN / 32, CD / 32), 256, 0, stream>>>(
        fc1_w + (size_t)l * CD * CFFN, w12, CD, CFFN);
    k_cvtw<<<dim3(CD / 32, CFFN / 32), 256, 0, stream>>>(
        fc2_w + (size_t)l * CFFN * CD, w22, CFFN, CD);
  }

  k_scale<<<CB, 256, 0, stream>>>(x, scb, lgb);
  k_postab<<<CT, 512, 0, stream>>>(postab);

  const size_t US = (size_t)CT * 1024;  // split ushorts per batch elem (K=512)

  for (int b0 = 0; b0 < CB; b0 += Bc) {
    const int Mc = Bc * CT;

    // pointer roles this chunk (rotated per layer): HP=h, SA/SB=scratch (adjacent pair)
    float* HP = P0;
    float* SA = P1;
    float* SB = P2;

    k_embed<<<Mc, 128, 0, stream>>>(x + (size_t)b0 * CT * CCH, scb + b0 * CCH,
                                    lgb + b0 * CCH, emb_w, postab, emb_g, emb_b, HP, R0);

    for (int l = 0; l < CL; ++l) {
      const float* bq = attn_b + (size_t)(l * 4 + 0) * CD;
      const float* bk = attn_b + (size_t)(l * 4 + 1) * CD;
      const float* bv = attn_b + (size_t)(l * 4 + 2) * CD;
      const float* bo = attn_b + (size_t)(l * 4 + 3) * CD;
      const float* g0 = ln_g + (size_t)(l * 2 + 0) * CD;
      const float* be0 = ln_bb + (size_t)(l * 2 + 0) * CD;
      const float* g1 = ln_g + (size_t)(l * 2 + 1) * CD;
      const float* be1 = ln_bb + (size_t)(l * 2 + 1) * CD;
      const float* B1 = fc1_b + (size_t)l * CFFN;
      const float* B2f = fc2_b + (size_t)l * CD;
      const ushort* wq2 = W2b + l * LW;
      const ushort* wk2 = wq2 + WQ;
      const ushort* wv2 = wk2 + WQ;
      const ushort* wo2 = wv2 + WQ;
      const ushort* w12 = wo2 + WQ;
      const ushort* w22 = w12 + 2097152;

      float* Sbuf = (SA < SB) ? SA : SB;  // 4MB/b contiguous (adjacent pair)

      dim3 gP(CD / 64, Mc / 128);  // BNT=64 grid for N=512 GEMMs
      // Q,K projections -> split outputs (feed S GEMM)
      k_gemm2<4, 64><<<gP, 256, 0, stream>>>(R0, wq2, bq, nullptr, nullptr, R1,
                                             Mc, CD, CD, 0, 0, 0);
      k_gemm2<4, 64><<<gP, 256, 0, stream>>>(R0, wk2, bk, nullptr, nullptr, R2u,
                                             Mc, CD, CD, 0, 0, 0);
      // S = Q K^T (batched), fold, topk
      k_gemm2<3, 64><<<dim3(CT / 64, CT / 128, Bc), 256, 0, stream>>>(
          R1, R2u, nullptr, nullptr, Sbuf, nullptr, CT, CT, CD, US, US,
          (size_t)CT * CT);
      k_fold<<<dim3(CT / 64, Bc), 256, 0, stream>>>(Sbuf, corrb);
      k_topk<<<Bc, 1024, 0, stream>>>(corrb, wtb, idb);
      // V projection -> fp32 SA; aggregation -> split a2 (R1); O proj -> fp32 SB
      k_gemm2<0, 64><<<gP, 256, 0, stream>>>(R0, wv2, bv, nullptr, SA, nullptr,
                                             Mc, CD, CD, 0, 0, 0);
      k_agg<<<Mc, 128, 0, stream>>>(SA, wtb, idb, R1);
      k_gemm2<0, 64><<<gP, 256, 0, stream>>>(R1, wo2, bo, nullptr, SB, nullptr,
                                             Mc, CD, CD, 0, 0, 0);
      // residual + LN -> HP; decomp -> fp32 SA + split d2 (R2u)
      k_ln<1><<<Mc, 128, 0, stream>>>(HP, SB, g0, be0, HP);
      k_decomp<<<Mc, 128, 0, stream>>>(HP, SA, R2u);
      // FFN: FC1 (GELU, split out f2=RF), FC2 (+residual SA) -> HP
      k_gemm2<1, 128><<<dim3(CFFN / 128, Mc / 128), 256, 0, stream>>>(
          R2u, w12, B1, nullptr, nullptr, RF, Mc, CFFN, CD, 0, 0, 0);
      k_gemm2<2, 64><<<gP, 256, 0, stream>>>(RF, w22, B2f, SA, HP, nullptr,
                                             Mc, CD, CFFN, 0, 0, 0);
      // LN -> HP; decomp -> fp32 SB + split h2 (R0) for next layer
      k_ln<0><<<Mc, 128, 0, stream>>>(HP, nullptr, g1, be1, HP);
      k_decomp<<<Mc, 128, 0, stream>>>(HP, SB, R0);
      // rotate: (HP,SA,SB) <- (SB, HP, SA); keeps the free pair memory-adjacent
      float* t = HP;
      HP = SB;
      SB = SA;
      SA = t;
    }

    k_meant<<<Bc, 512, 0, stream>>>(HP, featb);
    k_head<<<Bc, 256, 0, stream>>>(featb, hw1, hb1, hw2, hb2, outp + (size_t)b0 * CNC);
  }
}

// Round 5
// 4837.723 us; speedup vs baseline: 3.3002x; 1.7138x over previous
//
#include <hip/hip_runtime.h>
#include <math.h>

#define CB 64      // batch
#define CT 1024    // time
#define CCH 12     // channels
#define CD 512     // d_model
#define CL 2       // layers
#define CFFN 2048
#define CFCH 256
#define CNC 5
#define CTOPK 20
#define CEPS 1e-5f

typedef __attribute__((ext_vector_type(8))) short bfrag;
typedef __attribute__((ext_vector_type(4))) float ffrag;

__device__ inline ushort bf16r(float f) {
  unsigned u = __float_as_uint(f);
  unsigned r = (u + 0x7FFFu + ((u >> 16) & 1u)) >> 16;
  return (ushort)r;
}
__device__ inline float bf16f(ushort h) { return __uint_as_float(((unsigned)h) << 16); }

// ---------------- mean-abs scaler ----------------
__global__ __launch_bounds__(256) void k_scale(const float* __restrict__ x,
                                               float* __restrict__ sc,
                                               float* __restrict__ lg) {
  int b = blockIdx.x, tid = threadIdx.x;
  float acc[CCH];
#pragma unroll
  for (int c = 0; c < CCH; ++c) acc[c] = 0.f;
  const float* xb = x + (size_t)b * CT * CCH;
  for (int t = tid; t < CT; t += 256) {
    const float* row = xb + t * CCH;
#pragma unroll
    for (int c = 0; c < CCH; ++c) acc[c] += fabsf(row[c]);
  }
  __shared__ float red[256][CCH];
#pragma unroll
  for (int c = 0; c < CCH; ++c) red[tid][c] = acc[c];
  __syncthreads();
  for (int off = 128; off > 0; off >>= 1) {
    if (tid < off) {
#pragma unroll
      for (int c = 0; c < CCH; ++c) red[tid][c] += red[tid + off][c];
    }
    __syncthreads();
  }
  if (tid < CCH) {
    float s = fmaxf(red[0][tid] * (1.0f / CT), 1e-10f);
    sc[b * CCH + tid] = s;
    lg[b * CCH + tid] = logf(s);
  }
}

// ---------------- sinusoidal position table (f64, matches np) ----------------
__global__ __launch_bounds__(512) void k_postab(float* __restrict__ pos) {
  int t = blockIdx.x;
  int d = threadIdx.x;
  double v;
  if (d < 256) {
    double w = pow(10000.0, -((double)d) / 256.0);
    v = sin((double)t * w);
  } else {
    double w = pow(10000.0, -((double)(d - 256)) / 256.0);
    v = cos((double)t * w);
  }
  pos[(size_t)t * CD + d] = (float)v;
}

// ---------------- embedding + LN fused; writes fp32 h AND bf16 h2 -------------------
__global__ __launch_bounds__(128) void k_embed(const float* __restrict__ x,
                                               const float* __restrict__ sc,
                                               const float* __restrict__ lg,
                                               const float* __restrict__ W,
                                               const float* __restrict__ postab,
                                               const float* __restrict__ g,
                                               const float* __restrict__ beta,
                                               float* __restrict__ h,
                                               ushort* __restrict__ h2) {
  int row = blockIdx.x;  // local: b*T + t
  int b = row >> 10, t = row & 1023;
  int tid = threadIdx.x;
  __shared__ float xs[CCH], ls[CCH];
  if (tid < CCH) {
    float s = sc[b * CCH + tid];
    xs[tid] = x[(size_t)row * CCH + tid] / s;
    ls[tid] = lg[b * CCH + tid];
  }
  __syncthreads();
  int d0 = tid * 4;
  float4 p = *(const float4*)(postab + (size_t)t * CD + d0);
  float v0 = p.x, v1 = p.y, v2 = p.z, v3 = p.w;
#pragma unroll
  for (int c = 0; c < CCH; ++c) {
    float xc = xs[c], lc = ls[c];
    float4 w0 = *(const float4*)(W + (size_t)c * CD + d0);
    float4 w1 = *(const float4*)(W + (size_t)(24 + c) * CD + d0);
    v0 += xc * w0.x + lc * w1.x;
    v1 += xc * w0.y + lc * w1.y;
    v2 += xc * w0.z + lc * w1.z;
    v3 += xc * w0.w + lc * w1.w;
  }
  float s1 = v0 + v1 + v2 + v3;
  float s2 = v0 * v0 + v1 * v1 + v2 * v2 + v3 * v3;
  for (int off = 32; off > 0; off >>= 1) {
    s1 += __shfl_down(s1, off);
    s2 += __shfl_down(s2, off);
  }
  __shared__ float ws1[2], ws2[2], mv[2];
  int wid = tid >> 6, lane = tid & 63;
  if (lane == 0) { ws1[wid] = s1; ws2[wid] = s2; }
  __syncthreads();
  if (tid == 0) {
    float S1 = ws1[0] + ws1[1], S2 = ws2[0] + ws2[1];
    float mu = S1 * (1.0f / CD);
    float var = S2 * (1.0f / CD) - mu * mu;
    mv[0] = mu;
    mv[1] = 1.0f / sqrtf(var + CEPS);
  }
  __syncthreads();
  float mu = mv[0], ri = mv[1];
  float4 gg = *(const float4*)(g + d0);
  float4 bb = *(const float4*)(beta + d0);
  float4 o;
  o.x = (v0 - mu) * ri * gg.x + bb.x;
  o.y = (v1 - mu) * ri * gg.y + bb.y;
  o.z = (v2 - mu) * ri * gg.z + bb.z;
  o.w = (v3 - mu) * ri * gg.w + bb.w;
  *(float4*)(h + (size_t)row * CD + d0) = o;
  ushort4 hv = {bf16r(o.x), bf16r(o.y), bf16r(o.z), bf16r(o.w)};
  *(ushort4*)(h2 + (size_t)row * CD + d0) = hv;
}

// ---------------- weight convert+transpose: W[K][N] fp32 -> W2[N][K] bf16 -----------
__global__ __launch_bounds__(256) void k_cvtw(const float* __restrict__ W,
                                              ushort* __restrict__ W2,
                                              int K, int N) {
  __shared__ float tile[32][33];
  int tx = threadIdx.x & 31, ty = threadIdx.x >> 5;  // ty 0..7
  int n0 = blockIdx.x * 32, k0 = blockIdx.y * 32;
#pragma unroll
  for (int r = 0; r < 4; ++r)
    tile[ty * 4 + r][tx] = W[(size_t)(k0 + ty * 4 + r) * N + n0 + tx];
  __syncthreads();
#pragma unroll
  for (int r = 0; r < 4; ++r) {
    int nl = ty * 4 + r, kl = tx;
    W2[(size_t)(n0 + nl) * K + k0 + kl] = bf16r(tile[kl][nl]);
  }
}

// ---------------- single-bf16 MFMA GEMM ---------------------------------------------
// A: [M][K] bf16 k-contig, W: [N][K] bf16 k-contig. fp32 MFMA accumulate.
// EPI: 0=bias->fp32  1=bias+GELU->bf16  2=bias+residual->fp32  3=raw->bf16 (S)
//      4=bias->bf16
#define LSTR 40  // LDS row stride (ushorts): 16B-aligned, <=2-way read conflicts
template <int EPI, int BNT>
__global__ __launch_bounds__(256) void k_gemm3(const ushort* __restrict__ A,
                                               const ushort* __restrict__ W,
                                               const float* __restrict__ bias,
                                               const float* __restrict__ R,
                                               float* __restrict__ Cout,
                                               ushort* __restrict__ Cs,
                                               int N, int K,
                                               size_t aBatch, size_t wBatch,
                                               size_t cBatch) {
  constexpr int MT = (BNT == 128) ? 4 : 2;  // 16-row m-tiles per wave
  __shared__ short Ah[128 * LSTR];
  __shared__ short Bh[BNT * LSTR];
  int tid = threadIdx.x;
  int n0 = blockIdx.x * BNT, m0 = blockIdx.y * 128;
  int w = tid >> 6, lane = tid & 63;
  int wm = (BNT == 128) ? (w >> 1) : w;
  int wn = (BNT == 128) ? (w & 1) : 0;
  int mOff = wm * MT * 16, nOff = wn * 64;
  int quad = lane >> 4, l16 = lane & 15;

  const ushort* Az = A + (size_t)blockIdx.z * aBatch;
  const ushort* Wz = W + (size_t)blockIdx.z * wBatch;

  ffrag acc[MT][4];
#pragma unroll
  for (int i = 0; i < MT; ++i)
#pragma unroll
    for (int j = 0; j < 4; ++j) acc[i][j] = (ffrag)(0.f);

  int sr = tid >> 2, sc = (tid & 3) * 8;
  const ushort* gA0 = Az + (size_t)(m0 + sr) * K + sc;
  const ushort* gA1 = Az + (size_t)(m0 + sr + 64) * K + sc;
  const ushort* gB0 = Wz + (size_t)(n0 + sr) * K + sc;
  const ushort* gB1 = Wz + (size_t)(n0 + ((BNT == 128) ? sr + 64 : sr)) * K + sc;
  int ld0 = sr * LSTR + sc, ld1 = (sr + 64) * LSTR + sc;

  for (int k0 = 0; k0 < K; k0 += 32) {
    *(uint4*)&Ah[ld0] = *(const uint4*)(gA0 + k0);
    *(uint4*)&Ah[ld1] = *(const uint4*)(gA1 + k0);
    *(uint4*)&Bh[ld0] = *(const uint4*)(gB0 + k0);
    if (BNT == 128) *(uint4*)&Bh[ld1] = *(const uint4*)(gB1 + k0);
    __syncthreads();

    bfrag ah[MT], bh[4];
#pragma unroll
    for (int i = 0; i < MT; ++i)
      ah[i] = *(const bfrag*)&Ah[(mOff + i * 16 + l16) * LSTR + quad * 8];
#pragma unroll
    for (int j = 0; j < 4; ++j)
      bh[j] = *(const bfrag*)&Bh[(nOff + j * 16 + l16) * LSTR + quad * 8];
#pragma unroll
    for (int i = 0; i < MT; ++i)
#pragma unroll
      for (int j = 0; j < 4; ++j)
        acc[i][j] = __builtin_amdgcn_mfma_f32_16x16x32_bf16(ah[i], bh[j], acc[i][j], 0, 0, 0);
    __syncthreads();
  }

  // epilogue: C tile layout col = lane&15, row = quad*4 + reg (verified R3/R4)
  size_t cb = (size_t)blockIdx.z * cBatch;
#pragma unroll
  for (int j = 0; j < 4; ++j) {
    int col = n0 + nOff + j * 16 + l16;
    float bcol = (EPI == 3) ? 0.f : bias[col];
#pragma unroll
    for (int i = 0; i < MT; ++i) {
      int rowb = m0 + mOff + i * 16 + quad * 4;
#pragma unroll
      for (int r = 0; r < 4; ++r) {
        int row = rowb + r;
        float vv = acc[i][j][r] + bcol;
        if (EPI == 1) vv = 0.5f * vv * (1.0f + erff(vv * 0.7071067811865475f));
        if (EPI == 2) vv += R[(size_t)row * N + col];
        if (EPI == 1 || EPI == 3 || EPI == 4)
          Cs[cb + (size_t)row * N + col] = bf16r(vv);
        else
          Cout[cb + (size_t)row * N + col] = vv;
      }
    }
  }
}

// ---------------- diagonal fold (bf16 S): corr[b,tau]=(1/512)sum_j S[(tau+j)%T,j] ---
__global__ __launch_bounds__(256) void k_fold(const ushort* __restrict__ S,
                                              float* __restrict__ corrb) {
  int b = blockIdx.y, tau0 = blockIdx.x * 64;
  int tid = threadIdx.x;
  int tl = tid & 63, p = tid >> 6;
  __shared__ float Sb[128][65];
  __shared__ float red[4][64];
  const ushort* Sbase = S + (size_t)b * CT * CT;
  float acc = 0.f;
  for (int jc = 0; jc < 16; ++jc) {
    int jbase = jc * 64;
    __syncthreads();
    for (int rnd = 0; rnd < 8; ++rnd) {
      int rr = rnd * 16 + (tid >> 4);
      int c4 = (tid & 15) * 4;
      int gi = (tau0 + jbase + rr) & (CT - 1);
      ushort4 v = *(const ushort4*)(Sbase + (size_t)gi * CT + jbase + c4);
      Sb[rr][c4 + 0] = bf16f(v.x);
      Sb[rr][c4 + 1] = bf16f(v.y);
      Sb[rr][c4 + 2] = bf16f(v.z);
      Sb[rr][c4 + 3] = bf16f(v.w);
    }
    __syncthreads();
#pragma unroll
    for (int q = 0; q < 16; ++q) {
      int jl = p * 16 + q;
      acc += Sb[tl + jl][jl];
    }
  }
  red[p][tl] = acc;
  __syncthreads();
  if (tid < 64) {
    float s = red[0][tid] + red[1][tid] + red[2][tid] + red[3][tid];
    corrb[(size_t)b * CT + tau0 + tid] = s * (1.0f / 512.0f);
  }
}

// ---------------- top-k (k=20) + softmax, 1024 threads ----------------
__global__ __launch_bounds__(1024) void k_topk(const float* __restrict__ corrb,
                                               float* __restrict__ wts,
                                               int* __restrict__ idxs) {
  int b = blockIdx.x, tid = threadIdx.x;
  float cur = corrb[(size_t)b * CT + tid];
  __shared__ float swv[16];
  __shared__ int swi[16];
  __shared__ float selv[CTOPK];
  __shared__ int seli[CTOPK];
  int wid = tid >> 6, lane = tid & 63;
  for (int k = 0; k < CTOPK; ++k) {
    float bv = cur;
    int bi = tid;
#pragma unroll
    for (int off = 32; off > 0; off >>= 1) {
      float ov = __shfl_down(bv, off);
      int oi = __shfl_down(bi, off);
      if (ov > bv || (ov == bv && oi < bi)) { bv = ov; bi = oi; }
    }
    if (lane == 0) { swv[wid] = bv; swi[wid] = bi; }
    __syncthreads();
    if (tid == 0) {
      float mv = swv[0];
      int mi = swi[0];
      for (int q = 1; q < 16; ++q) {
        if (swv[q] > mv || (swv[q] == mv && swi[q] < mi)) { mv = swv[q]; mi = swi[q]; }
      }
      selv[k] = mv;
      seli[k] = mi;
    }
    __syncthreads();
    if (tid == seli[k]) cur = -INFINITY;
    __syncthreads();
  }
  if (tid == 0) {
    float mx = selv[0], sum = 0.f, e[CTOPK];
    for (int k = 0; k < CTOPK; ++k) {
      e[k] = expf(selv[k] - mx);
      sum += e[k];
    }
    float inv = 1.0f / sum;
    for (int k = 0; k < CTOPK; ++k) {
      wts[b * CTOPK + k] = e[k] * inv;
      idxs[b * CTOPK + k] = seli[k];
    }
  }
}

// ---------------- delay aggregation: bf16 V in -> bf16 out --------------------------
__global__ __launch_bounds__(128) void k_agg(const ushort* __restrict__ V,
                                             const float* __restrict__ wts,
                                             const int* __restrict__ idxs,
                                             ushort* __restrict__ out2) {
  int row = blockIdx.x;
  int b = row >> 10, t = row & 1023;
  int d0 = threadIdx.x * 4;
  const ushort* Vb = V + (size_t)b * CT * CD;
  float4 acc = {0.f, 0.f, 0.f, 0.f};
#pragma unroll
  for (int k = 0; k < CTOPK; ++k) {
    float w = wts[b * CTOPK + k];
    int r = t + idxs[b * CTOPK + k];
    if (r >= CT) r -= CT;
    ushort4 v = *(const ushort4*)(Vb + (size_t)r * CD + d0);
    acc.x += w * bf16f(v.x);
    acc.y += w * bf16f(v.y);
    acc.z += w * bf16f(v.z);
    acc.w += w * bf16f(v.w);
  }
  ushort4 hv = {bf16r(acc.x), bf16r(acc.y), bf16r(acc.z), bf16r(acc.w)};
  *(ushort4*)(out2 + (size_t)row * CD + d0) = hv;
}

// ---------------- LayerNorm (optional residual add) ----------------
template <int ADD>
__global__ __launch_bounds__(128) void k_ln(const float* __restrict__ X,
                                            const float* __restrict__ Rr,
                                            const float* __restrict__ g,
                                            const float* __restrict__ beta,
                                            float* __restrict__ out) {
  int row = blockIdx.x, tid = threadIdx.x;
  int d0 = tid * 4;
  float4 v = *(const float4*)(X + (size_t)row * CD + d0);
  if (ADD) {
    float4 r = *(const float4*)(Rr + (size_t)row * CD + d0);
    v.x += r.x; v.y += r.y; v.z += r.z; v.w += r.w;
  }
  float s1 = v.x + v.y + v.z + v.w;
  float s2 = v.x * v.x + v.y * v.y + v.z * v.z + v.w * v.w;
  for (int off = 32; off > 0; off >>= 1) {
    s1 += __shfl_down(s1, off);
    s2 += __shfl_down(s2, off);
  }
  __shared__ float ws1[2], ws2[2], mv[2];
  int wid = tid >> 6, lane = tid & 63;
  if (lane == 0) { ws1[wid] = s1; ws2[wid] = s2; }
  __syncthreads();
  if (tid == 0) {
    float S1 = ws1[0] + ws1[1], S2 = ws2[0] + ws2[1];
    float mu = S1 * (1.0f / CD);
    float var = S2 * (1.0f / CD) - mu * mu;
    mv[0] = mu;
    mv[1] = 1.0f / sqrtf(var + CEPS);
  }
  __syncthreads();
  float mu = mv[0], ri = mv[1];
  float4 gg = *(const float4*)(g + d0);
  float4 bb = *(const float4*)(beta + d0);
  float4 o;
  o.x = (v.x - mu) * ri * gg.x + bb.x;
  o.y = (v.y - mu) * ri * gg.y + bb.y;
  o.z = (v.z - mu) * ri * gg.z + bb.z;
  o.w = (v.w - mu) * ri * gg.w + bb.w;
  *(float4*)(out + (size_t)row * CD + d0) = o;
}

// ---------------- series decomp: fp32 out + bf16 out --------------------------------
__global__ __launch_bounds__(128) void k_decomp(const float* __restrict__ X,
                                                float* __restrict__ out,
                                                ushort* __restrict__ out2) {
  int row = blockIdx.x;
  int b = row >> 10, t = row & 1023;
  int d0 = threadIdx.x * 4;
  const float* xb = X + (size_t)b * CT * CD + d0;
  float4 s = {0.f, 0.f, 0.f, 0.f};
#pragma unroll
  for (int j = -12; j <= 12; ++j) {
    int tt = t + j;
    tt = tt < 0 ? 0 : (tt > CT - 1 ? CT - 1 : tt);
    float4 v = *(const float4*)(xb + (size_t)tt * CD);
    s.x += v.x; s.y += v.y; s.z += v.z; s.w += v.w;
  }
  float4 xv = *(const float4*)(xb + (size_t)t * CD);
  const float inv = 1.0f / 25.0f;
  float4 o = {xv.x - s.x * inv, xv.y - s.y * inv, xv.z - s.z * inv, xv.w - s.w * inv};
  *(float4*)(out + (size_t)row * CD + d0) = o;
  ushort4 hv = {bf16r(o.x), bf16r(o.y), bf16r(o.z), bf16r(o.w)};
  *(ushort4*)(out2 + (size_t)row * CD + d0) = hv;
}

// ---------------- time mean ----------------
__global__ __launch_bounds__(512) void k_meant(const float* __restrict__ X,
                                               float* __restrict__ feat) {
  int b = blockIdx.x, d = threadIdx.x;
  const float* xb = X + (size_t)b * CT * CD + d;
  float acc = 0.f;
  for (int t = 0; t < CT; ++t) acc += xb[(size_t)t * CD];
  feat[b * CD + d] = acc * (1.0f / CT);
}

// ---------------- classification head ----------------
__global__ __launch_bounds__(256) void k_head(const float* __restrict__ feat,
                                              const float* __restrict__ w1,
                                              const float* __restrict__ b1,
                                              const float* __restrict__ w2,
                                              const float* __restrict__ b2,
                                              float* __restrict__ out) {
  int b = blockIdx.x, tid = threadIdx.x;
  __shared__ float f[CD];
  __shared__ float hid[CFCH];
  for (int i = tid; i < CD; i += 256) f[i] = feat[b * CD + i];
  __syncthreads();
  float acc = b1[tid];
  for (int d = 0; d < CD; ++d) acc += f[d] * w1[d * CFCH + tid];
  hid[tid] = fmaxf(acc, 0.f);
  __syncthreads();
  if (tid < CNC) {
    float acc2 = b2[tid];
    for (int j = 0; j < CFCH; ++j) acc2 += hid[j] * w2[j * CNC + tid];
    out[b * CNC + tid] = acc2;
  }
}

// =====================================================================================
extern "C" void kernel_launch(void* const* d_in, const int* in_sizes, int n_in,
                              void* d_out, int out_size, void* d_ws, size_t ws_size,
                              hipStream_t stream) {
  const float* x = (const float*)d_in[0];
  const float* emb_w = (const float*)d_in[1];
  const float* emb_g = (const float*)d_in[2];
  const float* emb_b = (const float*)d_in[3];
  const float* attn_w = (const float*)d_in[4];
  const float* attn_b = (const float*)d_in[5];
  const float* ln_g = (const float*)d_in[6];
  const float* ln_bb = (const float*)d_in[7];
  const float* fc1_w = (const float*)d_in[8];
  const float* fc1_b = (const float*)d_in[9];
  const float* fc2_w = (const float*)d_in[10];
  const float* fc2_b = (const float*)d_in[11];
  const float* hw1 = (const float*)d_in[12];
  const float* hb1 = (const float*)d_in[13];
  const float* hw2 = (const float*)d_in[14];
  const float* hb2 = (const float*)d_in[15];
  float* outp = (float*)d_out;

  // per-layer bf16 weights (ushorts): wq,wk,wv,wo (512*512 each) + w1 + w2
  const size_t WQ = 262144ULL;                         // 512*512
  const size_t LW = 4 * WQ + 1048576ULL + 1048576ULL;  // 3,145,728 ushorts
  const size_t W2TOT = CL * LW;

  const size_t FIXED_B = W2TOT * 2                     // bf16 weights
                         + (size_t)CT * CD * 4         // postab
                         + 2 * (size_t)CB * CCH * 4    // sc,lg
                         + (size_t)CB * CT * 4         // corr
                         + 2 * (size_t)CB * CTOPK * 4  // wts,idxs
                         + (size_t)CB * CD * 4         // feat
                         + 4096;
  // per-b bytes: HP(2MB) SA(2MB, doubles as bf16 S) h2(1MB) q2(1MB) k2(1MB) f2(2MB)
  const size_t PERB = 2ULL * CT * CD * 4 + 3ULL * CT * CD * 2 + (size_t)CT * CFFN;
  int Bc = CB;
  while (Bc > 1) {
    if ((size_t)Bc * PERB + FIXED_B <= ws_size) break;
    Bc >>= 1;
  }
  const size_t CHF = (size_t)Bc * CT * CD;  // elems per (B,T,D) buffer

  char* wsp = (char*)d_ws;
  float* P0 = (float*)wsp;     wsp += CHF * 4;               // HP/SA ping
  float* P1 = (float*)wsp;     wsp += CHF * 4;               // HP/SA pong (S lives here)
  ushort* h2 = (ushort*)wsp;   wsp += CHF * 2;
  ushort* q2 = (ushort*)wsp;   wsp += CHF * 2;               // Q, then V
  ushort* k2 = (ushort*)wsp;   wsp += CHF * 2;               // K, then agg-out
  ushort* f2 = (ushort*)wsp;   wsp += (size_t)Bc * CT * CFFN; // FFN half-intermediate
  ushort* W2b = (ushort*)wsp;  wsp += W2TOT * 2;
  float* postab = (float*)wsp; wsp += (size_t)CT * CD * 4;
  float* scb = (float*)wsp;    wsp += (size_t)CB * CCH * 4;
  float* lgb = (float*)wsp;    wsp += (size_t)CB * CCH * 4;
  float* corrb = (float*)wsp;  wsp += (size_t)CB * CT * 4;
  float* wtb = (float*)wsp;    wsp += (size_t)CB * CTOPK * 4;
  int* idb = (int*)wsp;        wsp += (size_t)CB * CTOPK * 4;
  float* featb = (float*)wsp;

  // ---- convert all weights to transposed bf16 [N][K], once per call ----
  for (int l = 0; l < CL; ++l) {
    ushort* wq2 = W2b + l * LW;
    ushort* wk2 = wq2 + WQ;
    ushort* wv2 = wk2 + WQ;
    ushort* wo2 = wv2 + WQ;
    ushort* w12 = wo2 + WQ;
    ushort* w22 = w12 + 1048576;
    for (int m = 0; m < 4; ++m)
      k_cvtw<<<dim3(CD / 32, CD / 32), 256, 0, stream>>>(
          attn_w + ((size_t)(l * 4 + m)) * CD * CD, wq2 + m * WQ, CD, CD);
    k_cvtw<<<dim3(CFFN / 32, CD / 32), 256, 0, stream>>>(
        fc1_w + (size_t)l * CD * CFFN, w12, CD, CFFN);
    k_cvtw<<<dim3(CD / 32, CFFN / 32), 256, 0, stream>>>(
        fc2_w + (size_t)l * CFFN * CD, w22, CFFN, CD);
  }

  k_scale<<<CB, 256, 0, stream>>>(x, scb, lgb);
  k_postab<<<CT, 512, 0, stream>>>(postab);

  const size_t AE = (size_t)CT * CD;  // bf16 elems per batch elem

  for (int b0 = 0; b0 < CB; b0 += Bc) {
    const int Mc = Bc * CT;
    const int MH = Mc / 2;  // FFN M-half

    float* HP = P0;
    float* SA = P1;

    k_embed<<<Mc, 128, 0, stream>>>(x + (size_t)b0 * CT * CCH, scb + b0 * CCH,
                                    lgb + b0 * CCH, emb_w, postab, emb_g, emb_b,
                                    HP, h2);

    for (int l = 0; l < CL; ++l) {
      const float* bq = attn_b + (size_t)(l * 4 + 0) * CD;
      const float* bk = attn_b + (size_t)(l * 4 + 1) * CD;
      const float* bv = attn_b + (size_t)(l * 4 + 2) * CD;
      const float* bo = attn_b + (size_t)(l * 4 + 3) * CD;
      const float* g0 = ln_g + (size_t)(l * 2 + 0) * CD;
      const float* be0 = ln_bb + (size_t)(l * 2 + 0) * CD;
      const float* g1 = ln_g + (size_t)(l * 2 + 1) * CD;
      const float* be1 = ln_bb + (size_t)(l * 2 + 1) * CD;
      const float* B1 = fc1_b + (size_t)l * CFFN;
      const float* B2f = fc2_b + (size_t)l * CD;
      const ushort* wq2 = W2b + l * LW;
      const ushort* wk2 = wq2 + WQ;
      const ushort* wv2 = wk2 + WQ;
      const ushort* wo2 = wv2 + WQ;
      const ushort* w12 = wo2 + WQ;
      const ushort* w22 = w12 + 1048576;

      ushort* Sbuf = (ushort*)SA;  // Bc * CT*CT bf16 == Bc*2MB, exact fit

      dim3 gP(CD / 64, Mc / 128);
      // Q,K projections -> bf16
      k_gemm3<4, 64><<<gP, 256, 0, stream>>>(h2, wq2, bq, nullptr, nullptr, q2,
                                             CD, CD, 0, 0, 0);
      k_gemm3<4, 64><<<gP, 256, 0, stream>>>(h2, wk2, bk, nullptr, nullptr, k2,
                                             CD, CD, 0, 0, 0);
      // S = Q K^T (batched, bf16 out), fold, topk
      k_gemm3<3, 64><<<dim3(CT / 64, CT / 128, Bc), 256, 0, stream>>>(
          q2, k2, nullptr, nullptr, nullptr, Sbuf, CT, CD, AE, AE,
          (size_t)CT * CT);
      k_fold<<<dim3(CT / 64, Bc), 256, 0, stream>>>(Sbuf, corrb);
      k_topk<<<Bc, 1024, 0, stream>>>(corrb, wtb, idb);
      // V -> q2 (bf16); agg -> k2 (bf16); O -> SA (fp32)
      k_gemm3<4, 64><<<gP, 256, 0, stream>>>(h2, wv2, bv, nullptr, nullptr, q2,
                                             CD, CD, 0, 0, 0);
      k_agg<<<Mc, 128, 0, stream>>>(q2, wtb, idb, k2);
      k_gemm3<0, 64><<<gP, 256, 0, stream>>>(k2, wo2, bo, nullptr, SA, nullptr,
                                             CD, CD, 0, 0, 0);
      // residual + LN -> HP; decomp -> SA (fp32 res) + h2 (bf16 d2)
      k_ln<1><<<Mc, 128, 0, stream>>>(HP, SA, g0, be0, HP);
      k_decomp<<<Mc, 128, 0, stream>>>(HP, SA, h2);
      // FFN in two M-halves: FC1 (GELU -> bf16 f2), FC2 (+residual) -> HP
      for (int mh = 0; mh < 2; ++mh) {
        const ushort* inA = h2 + (size_t)mh * MH * CD;
        const float* res = SA + (size_t)mh * MH * CD;
        float* outc = HP + (size_t)mh * MH * CD;
        k_gemm3<1, 128><<<dim3(CFFN / 128, MH / 128), 256, 0, stream>>>(
            inA, w12, B1, nullptr, nullptr, f2, CFFN, CD, 0, 0, 0);
        k_gemm3<2, 64><<<dim3(CD / 64, MH / 128), 256, 0, stream>>>(
            f2, w22, B2f, res, outc, nullptr, CD, CFFN, 0, 0, 0);
      }
      // LN -> HP; decomp -> SA (next h fp32) + h2 (next h bf16); swap
      k_ln<0><<<Mc, 128, 0, stream>>>(HP, nullptr, g1, be1, HP);
      k_decomp<<<Mc, 128, 0, stream>>>(HP, SA, h2);
      float* t = HP;
      HP = SA;
      SA = t;
    }

    k_meant<<<Bc, 512, 0, stream>>>(HP, featb);
    k_head<<<Bc, 256, 0, stream>>>(featb, hw1, hb1, hw2, hb2, outp + (size_t)b0 * CNC);
  }
}

// Round 6
// 4684.899 us; speedup vs baseline: 3.4079x; 1.0326x over previous
//
#include <hip/hip_runtime.h>
#include <math.h>

#define CB 64      // batch
#define CT 1024    // time
#define CCH 12     // channels
#define CD 512     // d_model
#define CL 2       // layers
#define CFFN 2048
#define CFCH 256
#define CNC 5
#define CTOPK 20
#define CEPS 1e-5f

typedef __attribute__((ext_vector_type(8))) short bfrag;
typedef __attribute__((ext_vector_type(4))) float ffrag;

__device__ inline ushort bf16r(float f) {
  unsigned u = __float_as_uint(f);
  unsigned r = (u + 0x7FFFu + ((u >> 16) & 1u)) >> 16;
  return (ushort)r;
}
__device__ inline float bf16f(ushort h) { return __uint_as_float(((unsigned)h) << 16); }

// async 16B global->LDS (lds dest = wave-uniform base + lane*16)
__device__ __forceinline__ void gld16(const ushort* g, ushort* l) {
  __builtin_amdgcn_global_load_lds((__attribute__((address_space(1))) void*)g,
                                   (__attribute__((address_space(3))) void*)l,
                                   16, 0, 0);
}

// ---------------- mean-abs scaler ----------------
__global__ __launch_bounds__(256) void k_scale(const float* __restrict__ x,
                                               float* __restrict__ sc,
                                               float* __restrict__ lg) {
  int b = blockIdx.x, tid = threadIdx.x;
  float acc[CCH];
#pragma unroll
  for (int c = 0; c < CCH; ++c) acc[c] = 0.f;
  const float* xb = x + (size_t)b * CT * CCH;
  for (int t = tid; t < CT; t += 256) {
    const float* row = xb + t * CCH;
#pragma unroll
    for (int c = 0; c < CCH; ++c) acc[c] += fabsf(row[c]);
  }
  __shared__ float red[256][CCH];
#pragma unroll
  for (int c = 0; c < CCH; ++c) red[tid][c] = acc[c];
  __syncthreads();
  for (int off = 128; off > 0; off >>= 1) {
    if (tid < off) {
#pragma unroll
      for (int c = 0; c < CCH; ++c) red[tid][c] += red[tid + off][c];
    }
    __syncthreads();
  }
  if (tid < CCH) {
    float s = fmaxf(red[0][tid] * (1.0f / CT), 1e-10f);
    sc[b * CCH + tid] = s;
    lg[b * CCH + tid] = logf(s);
  }
}

// ---------------- sinusoidal position table (f64, matches np) ----------------
__global__ __launch_bounds__(512) void k_postab(float* __restrict__ pos) {
  int t = blockIdx.x;
  int d = threadIdx.x;
  double v;
  if (d < 256) {
    double w = pow(10000.0, -((double)d) / 256.0);
    v = sin((double)t * w);
  } else {
    double w = pow(10000.0, -((double)(d - 256)) / 256.0);
    v = cos((double)t * w);
  }
  pos[(size_t)t * CD + d] = (float)v;
}

// ---------------- embedding + LN fused; writes fp32 h AND bf16 h2 -------------------
__global__ __launch_bounds__(128) void k_embed(const float* __restrict__ x,
                                               const float* __restrict__ sc,
                                               const float* __restrict__ lg,
                                               const float* __restrict__ W,
                                               const float* __restrict__ postab,
                                               const float* __restrict__ g,
                                               const float* __restrict__ beta,
                                               float* __restrict__ h,
                                               ushort* __restrict__ h2) {
  int row = blockIdx.x;  // local: b*T + t
  int b = row >> 10, t = row & 1023;
  int tid = threadIdx.x;
  __shared__ float xs[CCH], ls[CCH];
  if (tid < CCH) {
    float s = sc[b * CCH + tid];
    xs[tid] = x[(size_t)row * CCH + tid] / s;
    ls[tid] = lg[b * CCH + tid];
  }
  __syncthreads();
  int d0 = tid * 4;
  float4 p = *(const float4*)(postab + (size_t)t * CD + d0);
  float v0 = p.x, v1 = p.y, v2 = p.z, v3 = p.w;
#pragma unroll
  for (int c = 0; c < CCH; ++c) {
    float xc = xs[c], lc = ls[c];
    float4 w0 = *(const float4*)(W + (size_t)c * CD + d0);
    float4 w1 = *(const float4*)(W + (size_t)(24 + c) * CD + d0);
    v0 += xc * w0.x + lc * w1.x;
    v1 += xc * w0.y + lc * w1.y;
    v2 += xc * w0.z + lc * w1.z;
    v3 += xc * w0.w + lc * w1.w;
  }
  float s1 = v0 + v1 + v2 + v3;
  float s2 = v0 * v0 + v1 * v1 + v2 * v2 + v3 * v3;
  for (int off = 32; off > 0; off >>= 1) {
    s1 += __shfl_down(s1, off);
    s2 += __shfl_down(s2, off);
  }
  __shared__ float ws1[2], ws2[2], mv[2];
  int wid = tid >> 6, lane = tid & 63;
  if (lane == 0) { ws1[wid] = s1; ws2[wid] = s2; }
  __syncthreads();
  if (tid == 0) {
    float S1 = ws1[0] + ws1[1], S2 = ws2[0] + ws2[1];
    float mu = S1 * (1.0f / CD);
    float var = S2 * (1.0f / CD) - mu * mu;
    mv[0] = mu;
    mv[1] = 1.0f / sqrtf(var + CEPS);
  }
  __syncthreads();
  float mu = mv[0], ri = mv[1];
  float4 gg = *(const float4*)(g + d0);
  float4 bb = *(const float4*)(beta + d0);
  float4 o;
  o.x = (v0 - mu) * ri * gg.x + bb.x;
  o.y = (v1 - mu) * ri * gg.y + bb.y;
  o.z = (v2 - mu) * ri * gg.z + bb.z;
  o.w = (v3 - mu) * ri * gg.w + bb.w;
  *(float4*)(h + (size_t)row * CD + d0) = o;
  ushort4 hv = {bf16r(o.x), bf16r(o.y), bf16r(o.z), bf16r(o.w)};
  *(ushort4*)(h2 + (size_t)row * CD + d0) = hv;
}

// ---------------- weight convert+transpose: W[K][N] fp32 -> W2[N][K] bf16 -----------
__global__ __launch_bounds__(256) void k_cvtw(const float* __restrict__ W,
                                              ushort* __restrict__ W2,
                                              int K, int N) {
  __shared__ float tile[32][33];
  int tx = threadIdx.x & 31, ty = threadIdx.x >> 5;  // ty 0..7
  int n0 = blockIdx.x * 32, k0 = blockIdx.y * 32;
#pragma unroll
  for (int r = 0; r < 4; ++r)
    tile[ty * 4 + r][tx] = W[(size_t)(k0 + ty * 4 + r) * N + n0 + tx];
  __syncthreads();
#pragma unroll
  for (int r = 0; r < 4; ++r) {
    int nl = ty * 4 + r, kl = tx;
    W2[(size_t)(n0 + nl) * K + k0 + kl] = bf16r(tile[kl][nl]);
  }
}

// ---------------- zero helper ----------------
__global__ __launch_bounds__(256) void k_zero(float* __restrict__ p, int n) {
  int i = blockIdx.x * 256 + threadIdx.x;
  if (i < n) p[i] = 0.f;
}

// ---------------- bf16 MFMA GEMM, 128x128 tile, global_load_lds staging -------------
// A: [M][lda] bf16 k-contig rows; W: [N][ldb] bf16 k-contig rows.
// EPI: 0=bias->fp32  1=bias+GELU->bf16  2=bias+residual->fp32  4=bias->bf16
//      5=S diagonal-fold (no C store; Cf = corr, atomic)
template <int EPI>
__global__ __launch_bounds__(256) void k_gemm3(const ushort* __restrict__ A,
                                               const ushort* __restrict__ W,
                                               const float* __restrict__ bias,
                                               const float* __restrict__ R,
                                               float* __restrict__ Cf,
                                               ushort* __restrict__ Cs,
                                               int lda, int ldb, int ldc, int K,
                                               size_t aBatch, size_t wBatch) {
  __shared__ ushort AhS[128 * 32];
  __shared__ ushort BhS[128 * 32];
  int tid = threadIdx.x;
  int n0 = blockIdx.x * 128, m0 = blockIdx.y * 128;
  int z = blockIdx.z;
  int wid = __builtin_amdgcn_readfirstlane(tid >> 6);
  int lane = tid & 63;
  int lr = lane >> 2, lc = (lane & 3) * 8;
  int wm = wid >> 1, wn = wid & 1;
  int mOff = wm * 64, nOff = wn * 64;
  int quad = lane >> 4, l16 = lane & 15;

  const ushort* Az = A + (size_t)z * aBatch;
  const ushort* Wz = W + (size_t)z * wBatch;
  const ushort* pA0 = Az + (size_t)(m0 + wid * 32 + lr) * lda + lc;
  const ushort* pA1 = pA0 + (size_t)16 * lda;
  const ushort* pB0 = Wz + (size_t)(n0 + wid * 32 + lr) * ldb + lc;
  const ushort* pB1 = pB0 + (size_t)16 * ldb;
  ushort* lA0 = AhS + wid * 32 * 32;
  ushort* lA1 = lA0 + 16 * 32;
  ushort* lB0 = BhS + wid * 32 * 32;
  ushort* lB1 = lB0 + 16 * 32;

  ffrag acc[4][4];
#pragma unroll
  for (int i = 0; i < 4; ++i)
#pragma unroll
    for (int j = 0; j < 4; ++j) acc[i][j] = (ffrag)(0.f);

  for (int k0 = 0; k0 < K; k0 += 32) {
    gld16(pA0 + k0, lA0);
    gld16(pA1 + k0, lA1);
    gld16(pB0 + k0, lB0);
    gld16(pB1 + k0, lB1);
    __syncthreads();
    bfrag ah[4], bh[4];
#pragma unroll
    for (int i = 0; i < 4; ++i)
      ah[i] = *(const bfrag*)&AhS[(mOff + i * 16 + l16) * 32 + quad * 8];
#pragma unroll
    for (int j = 0; j < 4; ++j)
      bh[j] = *(const bfrag*)&BhS[(nOff + j * 16 + l16) * 32 + quad * 8];
#pragma unroll
    for (int i = 0; i < 4; ++i)
#pragma unroll
      for (int j = 0; j < 4; ++j)
        acc[i][j] = __builtin_amdgcn_mfma_f32_16x16x32_bf16(ah[i], bh[j], acc[i][j], 0, 0, 0);
    __syncthreads();
  }

  if constexpr (EPI == 5) {
    // diagonal fold: corr[z, (m-n)%T] += acc/512  via LDS bins
    __shared__ float bins[256];
    bins[tid] = 0.f;
    __syncthreads();
    int base = 127 + mOff + quad * 4 - nOff - l16;
#pragma unroll
    for (int dd = -3; dd <= 3; ++dd) {
#pragma unroll
      for (int r = 0; r < 4; ++r) {
        float s = 0.f;
#pragma unroll
        for (int i = 0; i < 4; ++i) {
          int j = i - dd;
          if (j >= 0 && j < 4) s += acc[i][j][r];
        }
        atomicAdd(&bins[base + dd * 16 + r], s);
      }
    }
    __syncthreads();
    if (tid < 255) {
      float v = bins[tid];
      if (v != 0.f) {
        int diag = (m0 - n0 + tid - 127 + 2048) & (CT - 1);
        atomicAdd(&Cf[(size_t)z * CT + diag], v * (1.0f / 512.0f));
      }
    }
  } else {
    // C tile layout: col = lane&15, row = quad*4 + reg (verified R3-R5)
#pragma unroll
    for (int j = 0; j < 4; ++j) {
      int col = n0 + nOff + j * 16 + l16;
      float bcol = bias[col];
#pragma unroll
      for (int i = 0; i < 4; ++i) {
        int rowb = m0 + mOff + i * 16 + quad * 4;
#pragma unroll
        for (int r = 0; r < 4; ++r) {
          int row = rowb + r;
          float vv = acc[i][j][r] + bcol;
          if (EPI == 1) vv = 0.5f * vv * (1.0f + erff(vv * 0.7071067811865475f));
          if (EPI == 2) vv += R[(size_t)row * ldc + col];
          if (EPI == 1 || EPI == 4)
            Cs[(size_t)row * ldc + col] = bf16r(vv);
          else
            Cf[(size_t)row * ldc + col] = vv;
        }
      }
    }
  }
}

// ---------------- top-k (k=20) + softmax, 1024 threads ----------------
__global__ __launch_bounds__(1024) void k_topk(const float* __restrict__ corrb,
                                               float* __restrict__ wts,
                                               int* __restrict__ idxs) {
  int b = blockIdx.x, tid = threadIdx.x;
  float cur = corrb[(size_t)b * CT + tid];
  __shared__ float swv[16];
  __shared__ int swi[16];
  __shared__ float selv[CTOPK];
  __shared__ int seli[CTOPK];
  int wid = tid >> 6, lane = tid & 63;
  for (int k = 0; k < CTOPK; ++k) {
    float bv = cur;
    int bi = tid;
#pragma unroll
    for (int off = 32; off > 0; off >>= 1) {
      float ov = __shfl_down(bv, off);
      int oi = __shfl_down(bi, off);
      if (ov > bv || (ov == bv && oi < bi)) { bv = ov; bi = oi; }
    }
    if (lane == 0) { swv[wid] = bv; swi[wid] = bi; }
    __syncthreads();
    if (tid == 0) {
      float mv = swv[0];
      int mi = swi[0];
      for (int q = 1; q < 16; ++q) {
        if (swv[q] > mv || (swv[q] == mv && swi[q] < mi)) { mv = swv[q]; mi = swi[q]; }
      }
      selv[k] = mv;
      seli[k] = mi;
    }
    __syncthreads();
    if (tid == seli[k]) cur = -INFINITY;
    __syncthreads();
  }
  if (tid == 0) {
    float mx = selv[0], sum = 0.f, e[CTOPK];
    for (int k = 0; k < CTOPK; ++k) {
      e[k] = expf(selv[k] - mx);
      sum += e[k];
    }
    float inv = 1.0f / sum;
    for (int k = 0; k < CTOPK; ++k) {
      wts[b * CTOPK + k] = e[k] * inv;
      idxs[b * CTOPK + k] = seli[k];
    }
  }
}

// ---------------- delay aggregation: bf16 V (strided in qkv) -> bf16 out ------------
__global__ __launch_bounds__(128) void k_agg(const ushort* __restrict__ qkv,
                                             const float* __restrict__ wts,
                                             const int* __restrict__ idxs,
                                             ushort* __restrict__ out2) {
  int row = blockIdx.x;
  int b = row >> 10, t = row & 1023;
  int d0 = threadIdx.x * 4;
  const ushort* Vb = qkv + (size_t)b * CT * 1536 + 1024;
  float4 acc = {0.f, 0.f, 0.f, 0.f};
#pragma unroll
  for (int k = 0; k < CTOPK; ++k) {
    float w = wts[b * CTOPK + k];
    int r = t + idxs[b * CTOPK + k];
    if (r >= CT) r -= CT;
    ushort4 v = *(const ushort4*)(Vb + (size_t)r * 1536 + d0);
    acc.x += w * bf16f(v.x);
    acc.y += w * bf16f(v.y);
    acc.z += w * bf16f(v.z);
    acc.w += w * bf16f(v.w);
  }
  ushort4 hv = {bf16r(acc.x), bf16r(acc.y), bf16r(acc.z), bf16r(acc.w)};
  *(ushort4*)(out2 + (size_t)row * CD + d0) = hv;
}

// ---------------- LayerNorm (optional residual add) ----------------
template <int ADD>
__global__ __launch_bounds__(128) void k_ln(const float* __restrict__ X,
                                            const float* __restrict__ Rr,
                                            const float* __restrict__ g,
                                            const float* __restrict__ beta,
                                            float* __restrict__ out) {
  int row = blockIdx.x, tid = threadIdx.x;
  int d0 = tid * 4;
  float4 v = *(const float4*)(X + (size_t)row * CD + d0);
  if (ADD) {
    float4 r = *(const float4*)(Rr + (size_t)row * CD + d0);
    v.x += r.x; v.y += r.y; v.z += r.z; v.w += r.w;
  }
  float s1 = v.x + v.y + v.z + v.w;
  float s2 = v.x * v.x + v.y * v.y + v.z * v.z + v.w * v.w;
  for (int off = 32; off > 0; off >>= 1) {
    s1 += __shfl_down(s1, off);
    s2 += __shfl_down(s2, off);
  }
  __shared__ float ws1[2], ws2[2], mv[2];
  int wid = tid >> 6, lane = tid & 63;
  if (lane == 0) { ws1[wid] = s1; ws2[wid] = s2; }
  __syncthreads();
  if (tid == 0) {
    float S1 = ws1[0] + ws1[1], S2 = ws2[0] + ws2[1];
    float mu = S1 * (1.0f / CD);
    float var = S2 * (1.0f / CD) - mu * mu;
    mv[0] = mu;
    mv[1] = 1.0f / sqrtf(var + CEPS);
  }
  __syncthreads();
  float mu = mv[0], ri = mv[1];
  float4 gg = *(const float4*)(g + d0);
  float4 bb = *(const float4*)(beta + d0);
  float4 o;
  o.x = (v.x - mu) * ri * gg.x + bb.x;
  o.y = (v.y - mu) * ri * gg.y + bb.y;
  o.z = (v.z - mu) * ri * gg.z + bb.z;
  o.w = (v.w - mu) * ri * gg.w + bb.w;
  *(float4*)(out + (size_t)row * CD + d0) = o;
}

// ---------------- series decomp: fp32 out + bf16 out --------------------------------
__global__ __launch_bounds__(128) void k_decomp(const float* __restrict__ X,
                                                float* __restrict__ out,
                                                ushort* __restrict__ out2) {
  int row = blockIdx.x;
  int b = row >> 10, t = row & 1023;
  int d0 = threadIdx.x * 4;
  const float* xb = X + (size_t)b * CT * CD + d0;
  float4 s = {0.f, 0.f, 0.f, 0.f};
#pragma unroll
  for (int j = -12; j <= 12; ++j) {
    int tt = t + j;
    tt = tt < 0 ? 0 : (tt > CT - 1 ? CT - 1 : tt);
    float4 v = *(const float4*)(xb + (size_t)tt * CD);
    s.x += v.x; s.y += v.y; s.z += v.z; s.w += v.w;
  }
  float4 xv = *(const float4*)(xb + (size_t)t * CD);
  const float inv = 1.0f / 25.0f;
  float4 o = {xv.x - s.x * inv, xv.y - s.y * inv, xv.z - s.z * inv, xv.w - s.w * inv};
  *(float4*)(out + (size_t)row * CD + d0) = o;
  ushort4 hv = {bf16r(o.x), bf16r(o.y), bf16r(o.z), bf16r(o.w)};
  *(ushort4*)(out2 + (size_t)row * CD + d0) = hv;
}

// ---------------- time mean ----------------
__global__ __launch_bounds__(512) void k_meant(const float* __restrict__ X,
                                               float* __restrict__ feat) {
  int b = blockIdx.x, d = threadIdx.x;
  const float* xb = X + (size_t)b * CT * CD + d;
  float acc = 0.f;
  for (int t = 0; t < CT; ++t) acc += xb[(size_t)t * CD];
  feat[b * CD + d] = acc * (1.0f / CT);
}

// ---------------- classification head ----------------
__global__ __launch_bounds__(256) void k_head(const float* __restrict__ feat,
                                              const float* __restrict__ w1,
                                              const float* __restrict__ b1,
                                              const float* __restrict__ w2,
                                              const float* __restrict__ b2,
                                              float* __restrict__ out) {
  int b = blockIdx.x, tid = threadIdx.x;
  __shared__ float f[CD];
  __shared__ float hid[CFCH];
  for (int i = tid; i < CD; i += 256) f[i] = feat[b * CD + i];
  __syncthreads();
  float acc = b1[tid];
  for (int d = 0; d < CD; ++d) acc += f[d] * w1[d * CFCH + tid];
  hid[tid] = fmaxf(acc, 0.f);
  __syncthreads();
  if (tid < CNC) {
    float acc2 = b2[tid];
    for (int j = 0; j < CFCH; ++j) acc2 += hid[j] * w2[j * CNC + tid];
    out[b * CNC + tid] = acc2;
  }
}

// =====================================================================================
extern "C" void kernel_launch(void* const* d_in, const int* in_sizes, int n_in,
                              void* d_out, int out_size, void* d_ws, size_t ws_size,
                              hipStream_t stream) {
  const float* x = (const float*)d_in[0];
  const float* emb_w = (const float*)d_in[1];
  const float* emb_g = (const float*)d_in[2];
  const float* emb_b = (const float*)d_in[3];
  const float* attn_w = (const float*)d_in[4];
  const float* attn_b = (const float*)d_in[5];
  const float* ln_g = (const float*)d_in[6];
  const float* ln_bb = (const float*)d_in[7];
  const float* fc1_w = (const float*)d_in[8];
  const float* fc1_b = (const float*)d_in[9];
  const float* fc2_w = (const float*)d_in[10];
  const float* fc2_b = (const float*)d_in[11];
  const float* hw1 = (const float*)d_in[12];
  const float* hb1 = (const float*)d_in[13];
  const float* hw2 = (const float*)d_in[14];
  const float* hb2 = (const float*)d_in[15];
  float* outp = (float*)d_out;

  // per-layer bf16 weights (ushorts): wq,wk,wv (contig => fused QKV), wo, w1, w2
  const size_t WQ = 262144ULL;                         // 512*512
  const size_t LW = 4 * WQ + 1048576ULL + 1048576ULL;  // 3,145,728 ushorts
  const size_t W2TOT = CL * LW;

  const size_t FIXED_B = W2TOT * 2                     // bf16 weights
                         + (size_t)CT * CD * 4         // postab
                         + 2 * (size_t)CB * CCH * 4    // sc,lg
                         + (size_t)CB * CT * 4         // corr
                         + 2 * (size_t)CB * CTOPK * 4  // wts,idxs
                         + (size_t)CB * CD * 4         // feat
                         + 4096;
  // per-b bytes: HP(2MB) + SA(2MB) + U0 bf16 [T][512](1MB) + U1 bf16 [T][1536](3MB)
  const size_t PERB = 2ULL * CT * CD * 4 + (size_t)CT * CD * 2 + 3ULL * CT * CD * 2;
  int Bc = CB;
  while (Bc > 1) {
    if ((size_t)Bc * PERB + FIXED_B <= ws_size) break;
    Bc >>= 1;
  }
  const size_t CHF = (size_t)Bc * CT * CD;

  char* wsp = (char*)d_ws;
  float* P0 = (float*)wsp;     wsp += CHF * 4;
  float* P1 = (float*)wsp;     wsp += CHF * 4;
  ushort* U0 = (ushort*)wsp;   wsp += CHF * 2;       // h2 / agg-out / d2
  ushort* U1 = (ushort*)wsp;   wsp += CHF * 3 * 2;   // qkv [Mc][1536] / f2 [MH][2048]
  ushort* W2b = (ushort*)wsp;  wsp += W2TOT * 2;
  float* postab = (float*)wsp; wsp += (size_t)CT * CD * 4;
  float* scb = (float*)wsp;    wsp += (size_t)CB * CCH * 4;
  float* lgb = (float*)wsp;    wsp += (size_t)CB * CCH * 4;
  float* corrb = (float*)wsp;  wsp += (size_t)CB * CT * 4;
  float* wtb = (float*)wsp;    wsp += (size_t)CB * CTOPK * 4;
  int* idb = (int*)wsp;        wsp += (size_t)CB * CTOPK * 4;
  float* featb = (float*)wsp;

  // ---- convert all weights to transposed bf16 [N][K], once per call ----
  for (int l = 0; l < CL; ++l) {
    ushort* wq2 = W2b + l * LW;      // [1536][512] fused QKV (q,k,v contiguous)
    ushort* wo2 = wq2 + 3 * WQ;
    ushort* w12 = wo2 + WQ;
    ushort* w22 = w12 + 1048576;
    for (int m = 0; m < 4; ++m)
      k_cvtw<<<dim3(CD / 32, CD / 32), 256, 0, stream>>>(
          attn_w + ((size_t)(l * 4 + m)) * CD * CD, wq2 + m * WQ, CD, CD);
    k_cvtw<<<dim3(CFFN / 32, CD / 32), 256, 0, stream>>>(
        fc1_w + (size_t)l * CD * CFFN, w12, CD, CFFN);
    k_cvtw<<<dim3(CD / 32, CFFN / 32), 256, 0, stream>>>(
        fc2_w + (size_t)l * CFFN * CD, w22, CFFN, CD);
  }

  k_scale<<<CB, 256, 0, stream>>>(x, scb, lgb);
  k_postab<<<CT, 512, 0, stream>>>(postab);

  const size_t AE3 = (size_t)CT * 1536;  // qkv ushorts per batch elem

  for (int b0 = 0; b0 < CB; b0 += Bc) {
    const int Mc = Bc * CT;
    const int MH = Mc / 2;

    float* HP = P0;
    float* SA = P1;

    k_embed<<<Mc, 128, 0, stream>>>(x + (size_t)b0 * CT * CCH, scb + b0 * CCH,
                                    lgb + b0 * CCH, emb_w, postab, emb_g, emb_b,
                                    HP, U0);

    for (int l = 0; l < CL; ++l) {
      const float* bqkv = attn_b + (size_t)l * 4 * CD;  // q,k,v biases contiguous
      const float* bo = attn_b + (size_t)(l * 4 + 3) * CD;
      const float* g0 = ln_g + (size_t)(l * 2 + 0) * CD;
      const float* be0 = ln_bb + (size_t)(l * 2 + 0) * CD;
      const float* g1 = ln_g + (size_t)(l * 2 + 1) * CD;
      const float* be1 = ln_bb + (size_t)(l * 2 + 1) * CD;
      const float* B1 = fc1_b + (size_t)l * CFFN;
      const float* B2f = fc2_b + (size_t)l * CD;
      const ushort* wq2 = W2b + l * LW;
      const ushort* wo2 = wq2 + 3 * WQ;
      const ushort* w12 = wo2 + WQ;
      const ushort* w22 = w12 + 1048576;

      // fused QKV projection -> U1 [Mc][1536] bf16
      k_gemm3<4><<<dim3(1536 / 128, Mc / 128), 256, 0, stream>>>(
          U0, wq2, bqkv, nullptr, nullptr, U1, CD, CD, 1536, CD, 0, 0);
      // corr = diag-fold(Q K^T), computed in the S-GEMM epilogue (no S buffer)
      k_zero<<<(Bc * CT + 255) / 256, 256, 0, stream>>>(corrb, Bc * CT);
      k_gemm3<5><<<dim3(CT / 128, CT / 128, Bc), 256, 0, stream>>>(
          U1, U1 + 512, nullptr, nullptr, corrb, nullptr, 1536, 1536, 0, CD,
          AE3, AE3);
      k_topk<<<Bc, 1024, 0, stream>>>(corrb, wtb, idb);
      // delay aggregation (V strided inside qkv) -> U0; O proj -> SA (fp32)
      k_agg<<<Mc, 128, 0, stream>>>(U1, wtb, idb, U0);
      k_gemm3<0><<<dim3(CD / 128, Mc / 128), 256, 0, stream>>>(
          U0, wo2, bo, nullptr, SA, nullptr, CD, CD, CD, CD, 0, 0);
      // residual + LN -> HP; decomp -> SA (fp32 res) + U0 (bf16 d2)
      k_ln<1><<<Mc, 128, 0, stream>>>(HP, SA, g0, be0, HP);
      k_decomp<<<Mc, 128, 0, stream>>>(HP, SA, U0);
      // FFN in two M-halves: FC1 (GELU -> bf16 f2=U1), FC2 (+residual) -> HP
      for (int mh = 0; mh < 2; ++mh) {
        const ushort* inA = U0 + (size_t)mh * MH * CD;
        const float* res = SA + (size_t)mh * MH * CD;
        float* outc = HP + (size_t)mh * MH * CD;
        k_gemm3<1><<<dim3(CFFN / 128, MH / 128), 256, 0, stream>>>(
            inA, w12, B1, nullptr, nullptr, U1, CD, CD, CFFN, CD, 0, 0);
        k_gemm3<2><<<dim3(CD / 128, MH / 128), 256, 0, stream>>>(
            U1, w22, B2f, res, outc, nullptr, CFFN, CFFN, CD, CFFN, 0, 0);
      }
      // LN -> HP; decomp -> SA (next h fp32) + U0 (next h bf16); swap
      k_ln<0><<<Mc, 128, 0, stream>>>(HP, nullptr, g1, be1, HP);
      k_decomp<<<Mc, 128, 0, stream>>>(HP, SA, U0);
      float* t = HP;
      HP = SA;
      SA = t;
    }

    k_meant<<<Bc, 512, 0, stream>>>(HP, featb);
    k_head<<<Bc, 256, 0, stream>>>(featb, hw1, hb1, hw2, hb2, outp + (size_t)b0 * CNC);
  }
}

// Round 7
// 4076.590 us; speedup vs baseline: 3.9164x; 1.1492x over previous
//
#include <hip/hip_runtime.h>
#include <math.h>

#define CB 64      // batch
#define CT 1024    // time
#define CCH 12     // channels
#define CD 512     // d_model
#define CL 2       // layers
#define CFFN 2048
#define CFCH 256
#define CNC 5
#define CTOPK 20
#define CEPS 1e-5f

typedef __attribute__((ext_vector_type(8))) short bfrag;
typedef __attribute__((ext_vector_type(4))) float ffrag;

__device__ inline ushort bf16r(float f) {
  unsigned u = __float_as_uint(f);
  unsigned r = (u + 0x7FFFu + ((u >> 16) & 1u)) >> 16;
  return (ushort)r;
}
__device__ inline float bf16f(ushort h) { return __uint_as_float(((unsigned)h) << 16); }

// async 16B global->LDS (lds dest = wave-uniform base + lane*16)
__device__ __forceinline__ void gld16(const ushort* g, ushort* l) {
  __builtin_amdgcn_global_load_lds((__attribute__((address_space(1))) void*)g,
                                   (__attribute__((address_space(3))) void*)l,
                                   16, 0, 0);
}

// ---------------- mean-abs scaler ----------------
__global__ __launch_bounds__(256) void k_scale(const float* __restrict__ x,
                                               float* __restrict__ sc,
                                               float* __restrict__ lg) {
  int b = blockIdx.x, tid = threadIdx.x;
  float acc[CCH];
#pragma unroll
  for (int c = 0; c < CCH; ++c) acc[c] = 0.f;
  const float* xb = x + (size_t)b * CT * CCH;
  for (int t = tid; t < CT; t += 256) {
    const float* row = xb + t * CCH;
#pragma unroll
    for (int c = 0; c < CCH; ++c) acc[c] += fabsf(row[c]);
  }
  __shared__ float red[256][CCH];
#pragma unroll
  for (int c = 0; c < CCH; ++c) red[tid][c] = acc[c];
  __syncthreads();
  for (int off = 128; off > 0; off >>= 1) {
    if (tid < off) {
#pragma unroll
      for (int c = 0; c < CCH; ++c) red[tid][c] += red[tid + off][c];
    }
    __syncthreads();
  }
  if (tid < CCH) {
    float s = fmaxf(red[0][tid] * (1.0f / CT), 1e-10f);
    sc[b * CCH + tid] = s;
    lg[b * CCH + tid] = logf(s);
  }
}

// ---------------- sinusoidal position table (f64, matches np) ----------------
__global__ __launch_bounds__(512) void k_postab(float* __restrict__ pos) {
  int t = blockIdx.x;
  int d = threadIdx.x;
  double v;
  if (d < 256) {
    double w = pow(10000.0, -((double)d) / 256.0);
    v = sin((double)t * w);
  } else {
    double w = pow(10000.0, -((double)(d - 256)) / 256.0);
    v = cos((double)t * w);
  }
  pos[(size_t)t * CD + d] = (float)v;
}

// ---------------- embedding + LN fused; writes fp32 h AND bf16 h2 -------------------
__global__ __launch_bounds__(128) void k_embed(const float* __restrict__ x,
                                               const float* __restrict__ sc,
                                               const float* __restrict__ lg,
                                               const float* __restrict__ W,
                                               const float* __restrict__ postab,
                                               const float* __restrict__ g,
                                               const float* __restrict__ beta,
                                               float* __restrict__ h,
                                               ushort* __restrict__ h2) {
  int row = blockIdx.x;  // local: b*T + t
  int b = row >> 10, t = row & 1023;
  int tid = threadIdx.x;
  __shared__ float xs[CCH], ls[CCH];
  if (tid < CCH) {
    float s = sc[b * CCH + tid];
    xs[tid] = x[(size_t)row * CCH + tid] / s;
    ls[tid] = lg[b * CCH + tid];
  }
  __syncthreads();
  int d0 = tid * 4;
  float4 p = *(const float4*)(postab + (size_t)t * CD + d0);
  float v0 = p.x, v1 = p.y, v2 = p.z, v3 = p.w;
#pragma unroll
  for (int c = 0; c < CCH; ++c) {
    float xc = xs[c], lc = ls[c];
    float4 w0 = *(const float4*)(W + (size_t)c * CD + d0);
    float4 w1 = *(const float4*)(W + (size_t)(24 + c) * CD + d0);
    v0 += xc * w0.x + lc * w1.x;
    v1 += xc * w0.y + lc * w1.y;
    v2 += xc * w0.z + lc * w1.z;
    v3 += xc * w0.w + lc * w1.w;
  }
  float s1 = v0 + v1 + v2 + v3;
  float s2 = v0 * v0 + v1 * v1 + v2 * v2 + v3 * v3;
  for (int off = 32; off > 0; off >>= 1) {
    s1 += __shfl_down(s1, off);
    s2 += __shfl_down(s2, off);
  }
  __shared__ float ws1[2], ws2[2], mv[2];
  int wid = tid >> 6, lane = tid & 63;
  if (lane == 0) { ws1[wid] = s1; ws2[wid] = s2; }
  __syncthreads();
  if (tid == 0) {
    float S1 = ws1[0] + ws1[1], S2 = ws2[0] + ws2[1];
    float mu = S1 * (1.0f / CD);
    float var = S2 * (1.0f / CD) - mu * mu;
    mv[0] = mu;
    mv[1] = 1.0f / sqrtf(var + CEPS);
  }
  __syncthreads();
  float mu = mv[0], ri = mv[1];
  float4 gg = *(const float4*)(g + d0);
  float4 bb = *(const float4*)(beta + d0);
  float4 o;
  o.x = (v0 - mu) * ri * gg.x + bb.x;
  o.y = (v1 - mu) * ri * gg.y + bb.y;
  o.z = (v2 - mu) * ri * gg.z + bb.z;
  o.w = (v3 - mu) * ri * gg.w + bb.w;
  *(float4*)(h + (size_t)row * CD + d0) = o;
  ushort4 hv = {bf16r(o.x), bf16r(o.y), bf16r(o.z), bf16r(o.w)};
  *(ushort4*)(h2 + (size_t)row * CD + d0) = hv;
}

// ---------------- weight convert+transpose: W[K][N] fp32 -> W2[N][K] bf16 -----------
__global__ __launch_bounds__(256) void k_cvtw(const float* __restrict__ W,
                                              ushort* __restrict__ W2,
                                              int K, int N) {
  __shared__ float tile[32][33];
  int tx = threadIdx.x & 31, ty = threadIdx.x >> 5;  // ty 0..7
  int n0 = blockIdx.x * 32, k0 = blockIdx.y * 32;
#pragma unroll
  for (int r = 0; r < 4; ++r)
    tile[ty * 4 + r][tx] = W[(size_t)(k0 + ty * 4 + r) * N + n0 + tx];
  __syncthreads();
#pragma unroll
  for (int r = 0; r < 4; ++r) {
    int nl = ty * 4 + r, kl = tx;
    W2[(size_t)(n0 + nl) * K + k0 + kl] = bf16r(tile[kl][nl]);
  }
}

// ---------------- zero helper ----------------
__global__ __launch_bounds__(256) void k_zero(float* __restrict__ p, int n) {
  int i = blockIdx.x * 256 + threadIdx.x;
  if (i < n) p[i] = 0.f;
}

// ---------------- bf16 MFMA GEMM, 128x128 tile, BK=64, swizzled LDS -----------------
// A: [M][lda] bf16 k-contig rows; W: [N][ldb] bf16 k-contig rows.
// LDS layout: row stride 64 ushorts; 16B chunk c of row r stored at chunkpos c^(r&7)
// (global source permuted per lane since gld16 dest is fixed base+lane*16).
// EPI: 0=bias->fp32  1=bias+GELU->bf16  2=bias+residual->fp32  4=bias->bf16
//      5=S diagonal-fold (no C store; Cf = corr, atomic)
template <int EPI>
__global__ __launch_bounds__(256) void k_gemm3(const ushort* __restrict__ A,
                                               const ushort* __restrict__ W,
                                               const float* __restrict__ bias,
                                               const float* __restrict__ R,
                                               float* __restrict__ Cf,
                                               ushort* __restrict__ Cs,
                                               int lda, int ldb, int ldc, int K,
                                               size_t aBatch, size_t wBatch) {
  __shared__ ushort AhS[128 * 64];
  __shared__ ushort BhS[128 * 64];
  int tid = threadIdx.x;
  int n0 = blockIdx.x * 128, m0 = blockIdx.y * 128;
  int z = blockIdx.z;
  int wid = __builtin_amdgcn_readfirstlane(tid >> 6);
  int lane = tid & 63;
  int lr = lane >> 3;                    // row-sub 0..7 within an 8-row gld16 group
  int lc = ((lane & 7) ^ lr) * 8;        // swizzled source col (ushorts)
  int wm = wid >> 1, wn = wid & 1;
  int mOff = wm * 64, nOff = wn * 64;
  int quad = lane >> 4, l16 = lane & 15;

  const ushort* Az = A + (size_t)z * aBatch;
  const ushort* Wz = W + (size_t)z * wBatch;
  // wave wid stages rows [wid*32, wid*32+32) of A and B: 4 gld16 each (8 rows/gld16)
  const ushort* pA = Az + (size_t)(m0 + wid * 32 + lr) * lda + lc;
  const ushort* pB = Wz + (size_t)(n0 + wid * 32 + lr) * ldb + lc;
  ushort* lA = AhS + (wid * 32) * 64;
  ushort* lB = BhS + (wid * 32) * 64;

  ffrag acc[4][4];
#pragma unroll
  for (int i = 0; i < 4; ++i)
#pragma unroll
    for (int j = 0; j < 4; ++j) acc[i][j] = (ffrag)(0.f);

  for (int k0 = 0; k0 < K; k0 += 64) {
#pragma unroll
    for (int p = 0; p < 4; ++p) {
      gld16(pA + (size_t)(p * 8) * lda + k0, lA + p * 8 * 64);
      gld16(pB + (size_t)(p * 8) * ldb + k0, lB + p * 8 * 64);
    }
    __syncthreads();
#pragma unroll
    for (int h = 0; h < 2; ++h) {
      bfrag ah[4], bh[4];
#pragma unroll
      for (int i = 0; i < 4; ++i) {
        int row = mOff + i * 16 + l16;
        ah[i] = *(const bfrag*)&AhS[row * 64 + ((((h << 2) | quad)) ^ (row & 7)) * 8];
      }
#pragma unroll
      for (int j = 0; j < 4; ++j) {
        int row = nOff + j * 16 + l16;
        bh[j] = *(const bfrag*)&BhS[row * 64 + ((((h << 2) | quad)) ^ (row & 7)) * 8];
      }
#pragma unroll
      for (int i = 0; i < 4; ++i)
#pragma unroll
        for (int j = 0; j < 4; ++j)
          acc[i][j] = __builtin_amdgcn_mfma_f32_16x16x32_bf16(ah[i], bh[j], acc[i][j], 0, 0, 0);
    }
    __syncthreads();
  }

  if constexpr (EPI == 5) {
    // diagonal fold: corr[z, (m-n)%T] += acc/512  via LDS bins
    __shared__ float bins[256];
    bins[tid] = 0.f;
    __syncthreads();
    int base = 127 + mOff + quad * 4 - nOff - l16;
#pragma unroll
    for (int dd = -3; dd <= 3; ++dd) {
#pragma unroll
      for (int r = 0; r < 4; ++r) {
        float s = 0.f;
#pragma unroll
        for (int i = 0; i < 4; ++i) {
          int j = i - dd;
          if (j >= 0 && j < 4) s += acc[i][j][r];
        }
        atomicAdd(&bins[base + dd * 16 + r], s);
      }
    }
    __syncthreads();
    if (tid < 255) {
      float v = bins[tid];
      if (v != 0.f) {
        int diag = (m0 - n0 + tid - 127 + 2048) & (CT - 1);
        atomicAdd(&Cf[(size_t)z * CT + diag], v * (1.0f / 512.0f));
      }
    }
  } else {
    // C tile layout: col = lane&15, row = quad*4 + reg (verified R3-R6)
#pragma unroll
    for (int j = 0; j < 4; ++j) {
      int col = n0 + nOff + j * 16 + l16;
      float bcol = bias[col];
#pragma unroll
      for (int i = 0; i < 4; ++i) {
        int rowb = m0 + mOff + i * 16 + quad * 4;
#pragma unroll
        for (int r = 0; r < 4; ++r) {
          int row = rowb + r;
          float vv = acc[i][j][r] + bcol;
          if (EPI == 1) vv = 0.5f * vv * (1.0f + erff(vv * 0.7071067811865475f));
          if (EPI == 2) vv += R[(size_t)row * ldc + col];
          if (EPI == 1 || EPI == 4)
            Cs[(size_t)row * ldc + col] = bf16r(vv);
          else
            Cf[(size_t)row * ldc + col] = vv;
        }
      }
    }
  }
}

// ---------------- top-k (k=20) + softmax, 1024 threads ----------------
__global__ __launch_bounds__(1024) void k_topk(const float* __restrict__ corrb,
                                               float* __restrict__ wts,
                                               int* __restrict__ idxs) {
  int b = blockIdx.x, tid = threadIdx.x;
  float cur = corrb[(size_t)b * CT + tid];
  __shared__ float swv[16];
  __shared__ int swi[16];
  __shared__ float selv[CTOPK];
  __shared__ int seli[CTOPK];
  int wid = tid >> 6, lane = tid & 63;
  for (int k = 0; k < CTOPK; ++k) {
    float bv = cur;
    int bi = tid;
#pragma unroll
    for (int off = 32; off > 0; off >>= 1) {
      float ov = __shfl_down(bv, off);
      int oi = __shfl_down(bi, off);
      if (ov > bv || (ov == bv && oi < bi)) { bv = ov; bi = oi; }
    }
    if (lane == 0) { swv[wid] = bv; swi[wid] = bi; }
    __syncthreads();
    if (tid == 0) {
      float mv = swv[0];
      int mi = swi[0];
      for (int q = 1; q < 16; ++q) {
        if (swv[q] > mv || (swv[q] == mv && swi[q] < mi)) { mv = swv[q]; mi = swi[q]; }
      }
      selv[k] = mv;
      seli[k] = mi;
    }
    __syncthreads();
    if (tid == seli[k]) cur = -INFINITY;
    __syncthreads();
  }
  if (tid == 0) {
    float mx = selv[0], sum = 0.f, e[CTOPK];
    for (int k = 0; k < CTOPK; ++k) {
      e[k] = expf(selv[k] - mx);
      sum += e[k];
    }
    float inv = 1.0f / sum;
    for (int k = 0; k < CTOPK; ++k) {
      wts[b * CTOPK + k] = e[k] * inv;
      idxs[b * CTOPK + k] = seli[k];
    }
  }
}

// ---------------- delay aggregation: bf16 V (strided in qkv) -> bf16 out ------------
// XCD-swizzled so each XCD's L2 holds one batch's V slice at a time.
__global__ __launch_bounds__(128) void k_agg(const ushort* __restrict__ qkv,
                                             const float* __restrict__ wts,
                                             const int* __restrict__ idxs,
                                             ushort* __restrict__ out2) {
  int nb = gridDim.x;
  int blk = blockIdx.x;
  int row = (blk & 7) * (nb >> 3) + (blk >> 3);
  int b = row >> 10, t = row & 1023;
  int d0 = threadIdx.x * 4;
  const ushort* Vb = qkv + (size_t)b * CT * 1536 + 1024;
  float4 acc = {0.f, 0.f, 0.f, 0.f};
#pragma unroll
  for (int k = 0; k < CTOPK; ++k) {
    float w = wts[b * CTOPK + k];
    int r = t + idxs[b * CTOPK + k];
    if (r >= CT) r -= CT;
    ushort4 v = *(const ushort4*)(Vb + (size_t)r * 1536 + d0);
    acc.x += w * bf16f(v.x);
    acc.y += w * bf16f(v.y);
    acc.z += w * bf16f(v.z);
    acc.w += w * bf16f(v.w);
  }
  ushort4 hv = {bf16r(acc.x), bf16r(acc.y), bf16r(acc.z), bf16r(acc.w)};
  *(ushort4*)(out2 + (size_t)row * CD + d0) = hv;
}

// ---------------- LayerNorm (optional residual add) ----------------
template <int ADD>
__global__ __launch_bounds__(128) void k_ln(const float* __restrict__ X,
                                            const float* __restrict__ Rr,
                                            const float* __restrict__ g,
                                            const float* __restrict__ beta,
                                            float* __restrict__ out) {
  int row = blockIdx.x, tid = threadIdx.x;
  int d0 = tid * 4;
  float4 v = *(const float4*)(X + (size_t)row * CD + d0);
  if (ADD) {
    float4 r = *(const float4*)(Rr + (size_t)row * CD + d0);
    v.x += r.x; v.y += r.y; v.z += r.z; v.w += r.w;
  }
  float s1 = v.x + v.y + v.z + v.w;
  float s2 = v.x * v.x + v.y * v.y + v.z * v.z + v.w * v.w;
  for (int off = 32; off > 0; off >>= 1) {
    s1 += __shfl_down(s1, off);
    s2 += __shfl_down(s2, off);
  }
  __shared__ float ws1[2], ws2[2], mv[2];
  int wid = tid >> 6, lane = tid & 63;
  if (lane == 0) { ws1[wid] = s1; ws2[wid] = s2; }
  __syncthreads();
  if (tid == 0) {
    float S1 = ws1[0] + ws1[1], S2 = ws2[0] + ws2[1];
    float mu = S1 * (1.0f / CD);
    float var = S2 * (1.0f / CD) - mu * mu;
    mv[0] = mu;
    mv[1] = 1.0f / sqrtf(var + CEPS);
  }
  __syncthreads();
  float mu = mv[0], ri = mv[1];
  float4 gg = *(const float4*)(g + d0);
  float4 bb = *(const float4*)(beta + d0);
  float4 o;
  o.x = (v.x - mu) * ri * gg.x + bb.x;
  o.y = (v.y - mu) * ri * gg.y + bb.y;
  o.z = (v.z - mu) * ri * gg.z + bb.z;
  o.w = (v.w - mu) * ri * gg.w + bb.w;
  *(float4*)(out + (size_t)row * CD + d0) = o;
}

// ---------------- series decomp: fp32 out + bf16 out; XCD-swizzled ------------------
__global__ __launch_bounds__(128) void k_decomp(const float* __restrict__ X,
                                                float* __restrict__ out,
                                                ushort* __restrict__ out2) {
  int nb = gridDim.x;
  int blk = blockIdx.x;
  int row = (blk & 7) * (nb >> 3) + (blk >> 3);
  int b = row >> 10, t = row & 1023;
  int d0 = threadIdx.x * 4;
  const float* xb = X + (size_t)b * CT * CD + d0;
  float4 s = {0.f, 0.f, 0.f, 0.f};
#pragma unroll
  for (int j = -12; j <= 12; ++j) {
    int tt = t + j;
    tt = tt < 0 ? 0 : (tt > CT - 1 ? CT - 1 : tt);
    float4 v = *(const float4*)(xb + (size_t)tt * CD);
    s.x += v.x; s.y += v.y; s.z += v.z; s.w += v.w;
  }
  float4 xv = *(const float4*)(xb + (size_t)t * CD);
  const float inv = 1.0f / 25.0f;
  float4 o = {xv.x - s.x * inv, xv.y - s.y * inv, xv.z - s.z * inv, xv.w - s.w * inv};
  *(float4*)(out + (size_t)row * CD + d0) = o;
  ushort4 hv = {bf16r(o.x), bf16r(o.y), bf16r(o.z), bf16r(o.w)};
  *(ushort4*)(out2 + (size_t)row * CD + d0) = hv;
}

// ---------------- time mean ----------------
__global__ __launch_bounds__(512) void k_meant(const float* __restrict__ X,
                                               float* __restrict__ feat) {
  int b = blockIdx.x, d = threadIdx.x;
  const float* xb = X + (size_t)b * CT * CD + d;
  float acc = 0.f;
  for (int t = 0; t < CT; ++t) acc += xb[(size_t)t * CD];
  feat[b * CD + d] = acc * (1.0f / CT);
}

// ---------------- classification head ----------------
__global__ __launch_bounds__(256) void k_head(const float* __restrict__ feat,
                                              const float* __restrict__ w1,
                                              const float* __restrict__ b1,
                                              const float* __restrict__ w2,
                                              const float* __restrict__ b2,
                                              float* __restrict__ out) {
  int b = blockIdx.x, tid = threadIdx.x;
  __shared__ float f[CD];
  __shared__ float hid[CFCH];
  for (int i = tid; i < CD; i += 256) f[i] = feat[b * CD + i];
  __syncthreads();
  float acc = b1[tid];
  for (int d = 0; d < CD; ++d) acc += f[d] * w1[d * CFCH + tid];
  hid[tid] = fmaxf(acc, 0.f);
  __syncthreads();
  if (tid < CNC) {
    float acc2 = b2[tid];
    for (int j = 0; j < CFCH; ++j) acc2 += hid[j] * w2[j * CNC + tid];
    out[b * CNC + tid] = acc2;
  }
}

// =====================================================================================
extern "C" void kernel_launch(void* const* d_in, const int* in_sizes, int n_in,
                              void* d_out, int out_size, void* d_ws, size_t ws_size,
                              hipStream_t stream) {
  const float* x = (const float*)d_in[0];
  const float* emb_w = (const float*)d_in[1];
  const float* emb_g = (const float*)d_in[2];
  const float* emb_b = (const float*)d_in[3];
  const float* attn_w = (const float*)d_in[4];
  const float* attn_b = (const float*)d_in[5];
  const float* ln_g = (const float*)d_in[6];
  const float* ln_bb = (const float*)d_in[7];
  const float* fc1_w = (const float*)d_in[8];
  const float* fc1_b = (const float*)d_in[9];
  const float* fc2_w = (const float*)d_in[10];
  const float* fc2_b = (const float*)d_in[11];
  const float* hw1 = (const float*)d_in[12];
  const float* hb1 = (const float*)d_in[13];
  const float* hw2 = (const float*)d_in[14];
  const float* hb2 = (const float*)d_in[15];
  float* outp = (float*)d_out;

  // per-layer bf16 weights (ushorts): wq,wk,wv (contig => fused QKV), wo, w1, w2
  const size_t WQ = 262144ULL;                         // 512*512
  const size_t LW = 4 * WQ + 1048576ULL + 1048576ULL;  // 3,145,728 ushorts
  const size_t W2TOT = CL * LW;

  const size_t FIXED_B = W2TOT * 2                     // bf16 weights
                         + (size_t)CT * CD * 4         // postab
                         + 2 * (size_t)CB * CCH * 4    // sc,lg
                         + (size_t)CB * CT * 4         // corr
                         + 2 * (size_t)CB * CTOPK * 4  // wts,idxs
                         + (size_t)CB * CD * 4         // feat
                         + 4096;
  // per-b bytes: HP(2MB) + SA(2MB) + U0 bf16 [T][512](1MB) + U1 bf16 [T][1536](3MB)
  const size_t PERB = 2ULL * CT * CD * 4 + (size_t)CT * CD * 2 + 3ULL * CT * CD * 2;
  int Bc = CB;
  while (Bc > 1) {
    if ((size_t)Bc * PERB + FIXED_B <= ws_size) break;
    Bc >>= 1;
  }
  const size_t CHF = (size_t)Bc * CT * CD;

  char* wsp = (char*)d_ws;
  float* P0 = (float*)wsp;     wsp += CHF * 4;
  float* P1 = (float*)wsp;     wsp += CHF * 4;
  ushort* U0 = (ushort*)wsp;   wsp += CHF * 2;       // h2 / agg-out / d2
  ushort* U1 = (ushort*)wsp;   wsp += CHF * 3 * 2;   // qkv [Mc][1536] / f2 [MH][2048]
  ushort* W2b = (ushort*)wsp;  wsp += W2TOT * 2;
  float* postab = (float*)wsp; wsp += (size_t)CT * CD * 4;
  float* scb = (float*)wsp;    wsp += (size_t)CB * CCH * 4;
  float* lgb = (float*)wsp;    wsp += (size_t)CB * CCH * 4;
  float* corrb = (float*)wsp;  wsp += (size_t)CB * CT * 4;
  float* wtb = (float*)wsp;    wsp += (size_t)CB * CTOPK * 4;
  int* idb = (int*)wsp;        wsp += (size_t)CB * CTOPK * 4;
  float* featb = (float*)wsp;

  // ---- convert all weights to transposed bf16 [N][K], once per call ----
  for (int l = 0; l < CL; ++l) {
    ushort* wq2 = W2b + l * LW;      // [1536][512] fused QKV (q,k,v contiguous)
    ushort* wo2 = wq2 + 3 * WQ;
    ushort* w12 = wo2 + WQ;
    ushort* w22 = w12 + 1048576;
    for (int m = 0; m < 4; ++m)
      k_cvtw<<<dim3(CD / 32, CD / 32), 256, 0, stream>>>(
          attn_w + ((size_t)(l * 4 + m)) * CD * CD, wq2 + m * WQ, CD, CD);
    k_cvtw<<<dim3(CFFN / 32, CD / 32), 256, 0, stream>>>(
        fc1_w + (size_t)l * CD * CFFN, w12, CD, CFFN);
    k_cvtw<<<dim3(CD / 32, CFFN / 32), 256, 0, stream>>>(
        fc2_w + (size_t)l * CFFN * CD, w22, CFFN, CD);
  }

  k_scale<<<CB, 256, 0, stream>>>(x, scb, lgb);
  k_postab<<<CT, 512, 0, stream>>>(postab);

  const size_t AE3 = (size_t)CT * 1536;  // qkv ushorts per batch elem

  for (int b0 = 0; b0 < CB; b0 += Bc) {
    const int Mc = Bc * CT;
    const int MH = Mc / 2;

    float* HP = P0;
    float* SA = P1;

    k_embed<<<Mc, 128, 0, stream>>>(x + (size_t)b0 * CT * CCH, scb + b0 * CCH,
                                    lgb + b0 * CCH, emb_w, postab, emb_g, emb_b,
                                    HP, U0);

    for (int l = 0; l < CL; ++l) {
      const float* bqkv = attn_b + (size_t)l * 4 * CD;  // q,k,v biases contiguous
      const float* bo = attn_b + (size_t)(l * 4 + 3) * CD;
      const float* g0 = ln_g + (size_t)(l * 2 + 0) * CD;
      const float* be0 = ln_bb + (size_t)(l * 2 + 0) * CD;
      const float* g1 = ln_g + (size_t)(l * 2 + 1) * CD;
      const float* be1 = ln_bb + (size_t)(l * 2 + 1) * CD;
      const float* B1 = fc1_b + (size_t)l * CFFN;
      const float* B2f = fc2_b + (size_t)l * CD;
      const ushort* wq2 = W2b + l * LW;
      const ushort* wo2 = wq2 + 3 * WQ;
      const ushort* w12 = wo2 + WQ;
      const ushort* w22 = w12 + 1048576;

      // fused QKV projection -> U1 [Mc][1536] bf16
      k_gemm3<4><<<dim3(1536 / 128, Mc / 128), 256, 0, stream>>>(
          U0, wq2, bqkv, nullptr, nullptr, U1, CD, CD, 1536, CD, 0, 0);
      // corr = diag-fold(Q K^T), computed in the S-GEMM epilogue (no S buffer)
      k_zero<<<(Bc * CT + 255) / 256, 256, 0, stream>>>(corrb, Bc * CT);
      k_gemm3<5><<<dim3(CT / 128, CT / 128, Bc), 256, 0, stream>>>(
          U1, U1 + 512, nullptr, nullptr, corrb, nullptr, 1536, 1536, 0, CD,
          AE3, AE3);
      k_topk<<<Bc, 1024, 0, stream>>>(corrb, wtb, idb);
      // delay aggregation (V strided inside qkv) -> U0; O proj -> SA (fp32)
      k_agg<<<Mc, 128, 0, stream>>>(U1, wtb, idb, U0);
      k_gemm3<0><<<dim3(CD / 128, Mc / 128), 256, 0, stream>>>(
          U0, wo2, bo, nullptr, SA, nullptr, CD, CD, CD, CD, 0, 0);
      // residual + LN -> HP; decomp -> SA (fp32 res) + U0 (bf16 d2)
      k_ln<1><<<Mc, 128, 0, stream>>>(HP, SA, g0, be0, HP);
      k_decomp<<<Mc, 128, 0, stream>>>(HP, SA, U0);
      // FFN in two M-halves: FC1 (GELU -> bf16 f2=U1), FC2 (+residual) -> HP
      for (int mh = 0; mh < 2; ++mh) {
        const ushort* inA = U0 + (size_t)mh * MH * CD;
        const float* res = SA + (size_t)mh * MH * CD;
        float* outc = HP + (size_t)mh * MH * CD;
        k_gemm3<1><<<dim3(CFFN / 128, MH / 128), 256, 0, stream>>>(
            inA, w12, B1, nullptr, nullptr, U1, CD, CD, CFFN, CD, 0, 0);
        k_gemm3<2><<<dim3(CD / 128, MH / 128), 256, 0, stream>>>(
            U1, w22, B2f, res, outc, nullptr, CFFN, CFFN, CD, CFFN, 0, 0);
      }
      // LN -> HP; decomp -> SA (next h fp32) + U0 (next h bf16); swap
      k_ln<0><<<Mc, 128, 0, stream>>>(HP, nullptr, g1, be1, HP);
      k_decomp<<<Mc, 128, 0, stream>>>(HP, SA, U0);
      float* t = HP;
      HP = SA;
      SA = t;
    }

    k_meant<<<Bc, 512, 0, stream>>>(HP, featb);
    k_head<<<Bc, 256, 0, stream>>>(featb, hw1, hb1, hw2, hb2, outp + (size_t)b0 * CNC);
  }
}